// Round 2
// baseline (100412.946 us; speedup 1.0000x reference)
//
#include <hip/hip_runtime.h>
#include <stdint.h>

typedef unsigned short ushort_t;

#define DEVINL static __device__ __forceinline__

DEVINL float bits2f(unsigned int b) { union { unsigned int i; float f; } v; v.i = b; return v.f; }
DEVINL float bf2f(ushort_t u) { return bits2f(((unsigned int)u) << 16); }
DEVINL ushort_t f2bf(float x) {
  union { float f; unsigned int i; } v; v.f = x;
  return (ushort_t)((v.i + 0x7FFFu + ((v.i >> 16) & 1u)) >> 16);
}

constexpr int NB2 = 2;
constexpr int HH = 48, WW = 64, HW = 3072;
constexpr int NP = NB2 * HW;   // 6144 pyramid rows
constexpr int CFEAT = 256;
constexpr int ITERS = 12;

// ---------------------------------------------------------------------------
// dtype detector: bf16-interpret first 4096 halfwords of fmap1. True bf16
// N(0,1) data stays |x|<~6; f32 data's low halfwords produce NaN/inf/huge
// with overwhelming probability. flag=1 -> inputs are f32.
// ---------------------------------------------------------------------------
__global__ __launch_bounds__(256) void detect_k(const ushort_t* __restrict__ src,
                                                int* __restrict__ flag) {
  const int t = threadIdx.x;
  int bad = 0;
  for (int i = t; i < 4096; i += 256) {
    const float v = bf2f(src[i]);
    if (!(fabsf(v) < 1e30f)) bad = 1;  // catches NaN, inf, huge
  }
  __shared__ int s;
  if (t == 0) s = 0;
  __syncthreads();
  if (bad) atomicOr(&s, 1);
  __syncthreads();
  if (t == 0) *flag = s;
}

// ---------------------------------------------------------------------------
// convert all 36 input tensors to f32 workspace copies (dual dtype mode)
// ---------------------------------------------------------------------------
struct CvtArgs {
  const void* src[36];
  float* dst[36];
  int n[36];
};
__global__ __launch_bounds__(256) void cvt_all_k(CvtArgs a, const int* __restrict__ flag) {
  const bool isf32 = (*flag != 0);
  const int stride = gridDim.x * 256;
  const int t0 = blockIdx.x * 256 + threadIdx.x;
  for (int s = 0; s < 36; ++s) {
    float* dst = a.dst[s];
    const int n = a.n[s];
    if (isf32) {
      const float* src = (const float*)a.src[s];
      for (int i = t0; i < n; i += stride) dst[i] = src[i];
    } else {
      const ushort_t* src = (const ushort_t*)a.src[s];
      for (int i = t0; i < n; i += stride) dst[i] = bf2f(src[i]);
    }
  }
}

// ---------------------------------------------------------------------------
// Correlation GEMM: corr[nb][i][j] = (1/16) * sum_c f1[nb,c,i] * f2[nb,c,j]
// f1,f2: f32 (NB2, 256, HW). out: bf16 (NB2*HW, HW).
// grid (48,48,NB2), block 256. 64x64 tile, 4x4 per thread.
// ---------------------------------------------------------------------------
__global__ __launch_bounds__(256) void corr_gemm_k(const float* __restrict__ f1,
                                                   const float* __restrict__ f2,
                                                   ushort_t* __restrict__ out) {
  const int nb = blockIdx.z;
  const int m0 = blockIdx.x * 64, n0 = blockIdx.y * 64;
  const int tid = threadIdx.x;
  const int tx = tid & 15, ty = tid >> 4;
  __shared__ __align__(16) float As[16][64];
  __shared__ __align__(16) float Bs[16][64];
  const float* pa = f1 + (size_t)nb * CFEAT * HW;
  const float* pb = f2 + (size_t)nb * CFEAT * HW;
  const int lr = tid >> 4;
  const int lc = (tid & 15) * 4;
  float acc[4][4];
#pragma unroll
  for (int i = 0; i < 4; ++i)
#pragma unroll
    for (int j = 0; j < 4; ++j) acc[i][j] = 0.f;

  for (int k0 = 0; k0 < CFEAT; k0 += 16) {
    const float4 va = *(const float4*)(pa + (size_t)(k0 + lr) * HW + m0 + lc);
    const float4 vb = *(const float4*)(pb + (size_t)(k0 + lr) * HW + n0 + lc);
    __syncthreads();
    As[lr][lc + 0] = va.x;
    As[lr][lc + 1] = va.y;
    As[lr][lc + 2] = va.z;
    As[lr][lc + 3] = va.w;
    Bs[lr][lc + 0] = vb.x;
    Bs[lr][lc + 1] = vb.y;
    Bs[lr][lc + 2] = vb.z;
    Bs[lr][lc + 3] = vb.w;
    __syncthreads();
#pragma unroll
    for (int kk = 0; kk < 16; ++kk) {
      const float4 a = *(const float4*)&As[kk][ty * 4];
      const float4 b = *(const float4*)&Bs[kk][tx * 4];
      acc[0][0] = fmaf(a.x, b.x, acc[0][0]);
      acc[0][1] = fmaf(a.x, b.y, acc[0][1]);
      acc[0][2] = fmaf(a.x, b.z, acc[0][2]);
      acc[0][3] = fmaf(a.x, b.w, acc[0][3]);
      acc[1][0] = fmaf(a.y, b.x, acc[1][0]);
      acc[1][1] = fmaf(a.y, b.y, acc[1][1]);
      acc[1][2] = fmaf(a.y, b.z, acc[1][2]);
      acc[1][3] = fmaf(a.y, b.w, acc[1][3]);
      acc[2][0] = fmaf(a.z, b.x, acc[2][0]);
      acc[2][1] = fmaf(a.z, b.y, acc[2][1]);
      acc[2][2] = fmaf(a.z, b.z, acc[2][2]);
      acc[2][3] = fmaf(a.z, b.w, acc[2][3]);
      acc[3][0] = fmaf(a.w, b.x, acc[3][0]);
      acc[3][1] = fmaf(a.w, b.y, acc[3][1]);
      acc[3][2] = fmaf(a.w, b.z, acc[3][2]);
      acc[3][3] = fmaf(a.w, b.w, acc[3][3]);
    }
  }
#pragma unroll
  for (int ii = 0; ii < 4; ++ii)
#pragma unroll
    for (int jj = 0; jj < 4; ++jj) {
      const int mi = m0 + ty * 4 + ii;
      const int nj = n0 + tx * 4 + jj;
      out[((size_t)nb * HW + mi) * HW + nj] = f2bf(acc[ii][jj] * 0.0625f);
    }
}

// ---------------------------------------------------------------------------
// 2x2 avg-pool on (NP, hi, wi) bf16 -> (NP, ho, wo) bf16
// ---------------------------------------------------------------------------
__global__ __launch_bounds__(256) void avgpool_k(const ushort_t* __restrict__ in,
                                                 ushort_t* __restrict__ out,
                                                 int wi, int ho, int wo, int total) {
  int idx = blockIdx.x * 256 + threadIdx.x;
  if (idx >= total) return;
  int pw = ho * wo;
  int p = idx / pw;
  int r = idx - p * pw;
  int y = r / wo;
  int x = r - y * wo;
  const ushort_t* src = in + (size_t)p * (4 * pw) + (2 * y) * wi + 2 * x;
  float v = (bf2f(src[0]) + bf2f(src[1]) + bf2f(src[wi]) + bf2f(src[wi + 1])) * 0.25f;
  out[idx] = f2bf(v);
}

// ---------------------------------------------------------------------------
// Correlation lookup: out (NB2, 324, HW) fp32. grid (96, 81), block 256.
// thread: pixel p = bx*64 + (t&63), channel c = by*4 + (t>>6). c is wave-uniform.
// ---------------------------------------------------------------------------
__global__ __launch_bounds__(256) void lookup_k(
    const ushort_t* __restrict__ l0, const ushort_t* __restrict__ l1,
    const ushort_t* __restrict__ l2, const ushort_t* __restrict__ l3,
    const float* __restrict__ flow, float* __restrict__ out) {
  const int t = threadIdx.x;
  const int p = blockIdx.x * 64 + (t & 63);
  const int c = blockIdx.y * 4 + (t >> 6);
  const int nb = p / HW;
  const int rem = p - nb * HW;
  const int yy = rem >> 6, xx = rem & 63;
  const float fx = flow[((size_t)(nb * 2 + 0)) * HW + rem];
  const float fy = flow[((size_t)(nb * 2 + 1)) * HW + rem];
  const int l = c / 81;
  const int k = c - l * 81;
  const float dx = (float)(k / 9) - 4.f;        // x offset varies on first axis (RAFT layout)
  const float dy = (float)(k - (k / 9) * 9) - 4.f;
  const int hl = HH >> l, wl = WW >> l;
  const ushort_t* base = (l == 0) ? l0 : (l == 1) ? l1 : (l == 2) ? l2 : l3;
  const ushort_t* img = base + (size_t)p * (hl * wl);
  const float s = 1.f / (float)(1 << l);
  const float xl = ((float)xx + fx) * s + dx;
  const float yl = ((float)yy + fy) * s + dy;
  const float x0f = floorf(xl), y0f = floorf(yl);
  float acc = 0.f;
#pragma unroll
  for (int dy2 = 0; dy2 < 2; ++dy2) {
#pragma unroll
    for (int dx2 = 0; dx2 < 2; ++dx2) {
      const float xi = x0f + dx2, yi = y0f + dy2;
      if (xi >= 0.f && xi <= (float)(wl - 1) && yi >= 0.f && yi <= (float)(hl - 1)) {
        const float wv = (1.f - fabsf(xl - xi)) * (1.f - fabsf(yl - yi));
        acc += wv * bf2f(img[(int)yi * wl + (int)xi]);
      }
    }
  }
  out[((size_t)(nb * 324 + c)) * HW + rem] = acc;
}

// ---------------------------------------------------------------------------
// Generic direct conv. Input: (NB2, CI, 48, 64) fp32 (SPLIT: xa=128ch, xb=256ch
// concatenated logically). Weights fp32 (CO, CI, KH, KW). Output written into
// channel range [co_base, ...) of a (NB2, CO_TOT, 48, 64) tensor.
// Block: 256 threads, 64*4*PXPT pixels, OCPT output channels.
// ACT: 0 none, 1 relu, 2 sigmoid, 3 tanh.  out = act(acc + bias) * scale
// ---------------------------------------------------------------------------
template <int KH, int KW, int PH, int PW, int CSTEP, int OCPT, int PXPT, int ACT, bool SPLIT>
__global__ __launch_bounds__(256) void conv_k(
    const float* __restrict__ xa, const float* __restrict__ xb,
    const float* __restrict__ wgt, const float* __restrict__ bias,
    float* __restrict__ y, int CI, int co_base, int CO_TOT, float scale) {
  constexpr int ROWS = 4 * PXPT;
  constexpr int TR = ROWS + 2 * PH;
  constexpr int TC = 64 + 2 * PW;
  constexpr int TSZ = CSTEP * TR * TC;
  __shared__ float tile[TSZ];
  const int tid = threadIdx.x;
  const int nb = blockIdx.z;
  const int y0 = blockIdx.x * ROWS;
  const int co0 = blockIdx.y * OCPT;
  const int rxt = tid & 63;
  const int ryt = tid >> 6;
  float acc[OCPT][PXPT];
#pragma unroll
  for (int k = 0; k < OCPT; ++k)
#pragma unroll
    for (int px = 0; px < PXPT; ++px) acc[k][px] = 0.f;

  for (int c0 = 0; c0 < CI; c0 += CSTEP) {
    __syncthreads();
    for (int e = tid; e < TSZ; e += 256) {
      const int cl = e / (TR * TC);
      const int r = e - cl * (TR * TC);
      const int ry = r / TC;
      const int rx = r - ry * TC;
      const int gy = y0 - PH + ry;
      const int gx = rx - PW;
      float v = 0.f;
      if ((unsigned)gy < 48u && (unsigned)gx < 64u) {
        const int c = c0 + cl;
        if (SPLIT) {
          v = (c < 128) ? xa[((size_t)(nb * 128 + c)) * HW + gy * 64 + gx]
                        : xb[((size_t)(nb * 256 + (c - 128))) * HW + gy * 64 + gx];
        } else {
          v = xa[((size_t)(nb * CI + c)) * HW + gy * 64 + gx];
        }
      }
      tile[e] = v;
    }
    __syncthreads();
    const float* wp = wgt + ((size_t)co0 * CI + c0) * (KH * KW);
#pragma unroll
    for (int cl = 0; cl < CSTEP; ++cl) {
#pragma unroll
      for (int kh = 0; kh < KH; ++kh) {
#pragma unroll
        for (int kw = 0; kw < KW; ++kw) {
          float wv[OCPT];
#pragma unroll
          for (int k = 0; k < OCPT; ++k)
            wv[k] = wp[((size_t)k * CI + cl) * (KH * KW) + kh * KW + kw];
#pragma unroll
          for (int px = 0; px < PXPT; ++px) {
            const float v = tile[(cl * TR + ryt + px * 4 + kh) * TC + rxt + kw];
#pragma unroll
            for (int k = 0; k < OCPT; ++k) acc[k][px] = fmaf(wv[k], v, acc[k][px]);
          }
        }
      }
    }
  }
#pragma unroll
  for (int k = 0; k < OCPT; ++k) {
    const float b = bias[co0 + k];
#pragma unroll
    for (int px = 0; px < PXPT; ++px) {
      float v = acc[k][px] + b;
      if (ACT == 1) v = fmaxf(v, 0.f);
      if (ACT == 2) v = 1.f / (1.f + __expf(-v));
      if (ACT == 3) v = tanhf(v);
      v *= scale;
      y[((size_t)(nb * CO_TOT + co_base + co0 + k)) * HW + (y0 + ryt + px * 4) * 64 + rxt] = v;
    }
  }
}

// ---------------------------------------------------------------------------
// small elementwise kernels
// ---------------------------------------------------------------------------
__global__ __launch_bounds__(256) void init_k(const float* __restrict__ cnet,
                                              float* __restrict__ net, float* __restrict__ X) {
  int idx = blockIdx.x * 256 + threadIdx.x;  // NB2*128*HW
  if (idx >= NB2 * 128 * HW) return;
  int nb = idx / (128 * HW);
  int r = idx - nb * 128 * HW;
  int c = r / HW;
  int p = r - c * HW;
  float vn = cnet[((size_t)(nb * 256 + c)) * HW + p];
  float vi = cnet[((size_t)(nb * 256 + 128 + c)) * HW + p];
  net[idx] = tanhf(vn);
  X[((size_t)(nb * 256 + c)) * HW + p] = fmaxf(vi, 0.f);
}

__global__ __launch_bounds__(256) void gate_mul_k(float* __restrict__ r,
                                                  const float* __restrict__ net) {
  int i = blockIdx.x * 256 + threadIdx.x;
  if (i < NB2 * 128 * HW) r[i] *= net[i];
}

__global__ __launch_bounds__(256) void gru_update_k(float* __restrict__ net,
                                                    const float* __restrict__ z,
                                                    const float* __restrict__ q) {
  int i = blockIdx.x * 256 + threadIdx.x;
  if (i < NB2 * 128 * HW) {
    float zz = z[i];
    net[i] = (1.f - zz) * net[i] + zz * q[i];
  }
}

__global__ __launch_bounds__(256) void flow2x_k(const float* __restrict__ flow,
                                                float* __restrict__ X) {
  int i = blockIdx.x * 256 + threadIdx.x;  // NB2*2*HW
  if (i >= NB2 * 2 * HW) return;
  int nb = i / (2 * HW);
  int r = i - nb * 2 * HW;
  int ch = r / HW;
  int p = r - ch * HW;
  X[((size_t)(nb * 256 + 254 + ch)) * HW + p] = flow[i];
}

__global__ __launch_bounds__(256) void flow_update_k(float* __restrict__ flow,
                                                     float* __restrict__ eflow,
                                                     const float* __restrict__ df,
                                                     const float* __restrict__ edf) {
  int i = blockIdx.x * 256 + threadIdx.x;
  if (i < NB2 * 2 * HW) {
    float e = edf[i];
    flow[i] += df[i] + e;
    eflow[i] += e;
  }
}

// ---------------------------------------------------------------------------
// convex upsample. grid (2, 8, 96), block 256: t -> j = t&7, xh = t>>3.
// ---------------------------------------------------------------------------
__global__ __launch_bounds__(256) void upsample_k(const float* __restrict__ flow,
                                                  const float* __restrict__ mask,
                                                  float* __restrict__ out) {
  const int j = threadIdx.x & 7;
  const int xh = threadIdx.x >> 3;
  const int x = blockIdx.x * 32 + xh;
  const int i = blockIdx.y;
  const int nz = blockIdx.z;
  const int nb = nz / 48, yy = nz - nb * 48;
  const int rem = yy * 64 + x;
  float m[9];
  float mx = -1e30f;
#pragma unroll
  for (int k = 0; k < 9; ++k) {
    m[k] = mask[((size_t)(nb * 576 + k * 64 + i * 8 + j)) * HW + rem];
    mx = fmaxf(mx, m[k]);
  }
  float sum = 0.f;
#pragma unroll
  for (int k = 0; k < 9; ++k) {
    m[k] = __expf(m[k] - mx);
    sum += m[k];
  }
  const float inv = 8.f / sum;
#pragma unroll
  for (int ch = 0; ch < 2; ++ch) {
    float acc = 0.f;
#pragma unroll
    for (int k = 0; k < 9; ++k) {
      const int gy = yy + k / 3 - 1;
      const int gx = x + (k - (k / 3) * 3) - 1;
      float f = 0.f;
      if ((unsigned)gy < 48u && (unsigned)gx < 64u)
        f = flow[((size_t)(nb * 2 + ch)) * HW + gy * 64 + gx];
      acc = fmaf(m[k], f, acc);
    }
    out[(((size_t)(nb * 2 + ch)) * 384 + (yy * 8 + i)) * 512 + x * 8 + j] = acc * inv;
  }
}

// ---------------------------------------------------------------------------
// host orchestration
// ---------------------------------------------------------------------------
extern "C" void kernel_launch(void* const* d_in, const int* in_sizes, int n_in,
                              void* d_out, int out_size, void* d_ws, size_t ws_size,
                              hipStream_t stream) {
  (void)in_sizes; (void)n_in; (void)out_size;

  size_t off = 0;
  char* base = (char*)d_ws;
  auto take = [&](size_t nbytes) -> void* {
    void* p = base + off;
    off += (nbytes + 255) & ~(size_t)255;
    return p;
  };
  ushort_t* pyrA[4];
  ushort_t* pyrB[4];
  const int lsz[4] = {3072, 768, 192, 48};
  for (int l = 0; l < 4; ++l) pyrA[l] = (ushort_t*)take((size_t)NP * lsz[l] * 2);
  for (int l = 0; l < 4; ++l) pyrB[l] = (ushort_t*)take((size_t)NP * lsz[l] * 2);
  float* FM[6];  // f32 copies of fmap1, fmap2, fem1, fem2, cnet, enet
  for (int s = 0; s < 6; ++s) FM[s] = (float*)take((size_t)NB2 * 256 * HW * 4);
  float* CORR = (float*)take((size_t)NB2 * 324 * HW * 4);
  float* ECORR = (float*)take((size_t)NB2 * 324 * HW * 4);
  float* NET = (float*)take((size_t)NB2 * 128 * HW * 4);
  float* ENET = (float*)take((size_t)NB2 * 128 * HW * 4);
  float* X1 = (float*)take((size_t)NB2 * 256 * HW * 4);
  float* X2 = (float*)take((size_t)NB2 * 256 * HW * 4);
  float* FLOW = (float*)take((size_t)NB2 * 2 * HW * 4);
  float* EFLOW = (float*)take((size_t)NB2 * 2 * HW * 4);
  float* DF = (float*)take((size_t)NB2 * 2 * HW * 4);
  float* EDF = (float*)take((size_t)NB2 * 2 * HW * 4);
  float* FLO = (float*)take((size_t)NB2 * 128 * HW * 4);
  float* ZB = (float*)take((size_t)NB2 * 128 * HW * 4);
  float* RB = (float*)take((size_t)NB2 * 128 * HW * 4);
  float* QB = (float*)take((size_t)NB2 * 128 * HW * 4);
  float* A256 = (float*)take((size_t)NB2 * 256 * HW * 4);
  float* CFB = (float*)take((size_t)NB2 * 256 * HW * 4);
  float* MASK = (float*)take((size_t)NB2 * 576 * HW * 4);

  static const int WSZ[15] = {82944, 442368, 12544, 73728, 290304,
                              245760, 245760, 245760, 245760, 245760, 245760,
                              294912, 4608, 294912, 147456};
  static const int BSZ[15] = {256, 192, 128, 64, 126, 128, 128, 128,
                              128, 128, 128, 256, 2, 256, 576};
  float* Wf[15];
  float* Bf[15];
  for (int s = 0; s < 15; ++s) Wf[s] = (float*)take((size_t)WSZ[s] * 4);
  for (int s = 0; s < 15; ++s) Bf[s] = (float*)take((size_t)BSZ[s] * 4);
  int* FLAG = (int*)take(256);

  if (off > ws_size) return;  // workspace too small: fail loudly (wrong output)

  // dtype detection + unified f32 conversion of all inputs
  detect_k<<<1, 256, 0, stream>>>((const ushort_t*)d_in[0], FLAG);
  CvtArgs ca;
  for (int s = 0; s < 6; ++s) {
    ca.src[s] = d_in[s];
    ca.dst[s] = FM[s];
    ca.n[s] = NB2 * 256 * HW;
  }
  for (int s = 0; s < 15; ++s) {
    ca.src[6 + s] = d_in[6 + 2 * s];
    ca.dst[6 + s] = Wf[s];
    ca.n[6 + s] = WSZ[s];
    ca.src[21 + s] = d_in[7 + 2 * s];
    ca.dst[21 + s] = Bf[s];
    ca.n[21 + s] = BSZ[s];
  }
  cvt_all_k<<<1024, 256, 0, stream>>>(ca, FLAG);

  // correlation pyramids
  corr_gemm_k<<<dim3(48, 48, NB2), 256, 0, stream>>>(FM[0], FM[1], pyrA[0]);
  corr_gemm_k<<<dim3(48, 48, NB2), 256, 0, stream>>>(FM[2], FM[3], pyrB[0]);
  {
    const int wsv[4] = {64, 32, 16, 8};
    const int hsv[4] = {48, 24, 12, 6};
    for (int l = 0; l < 3; ++l) {
      int ho = hsv[l + 1], wo = wsv[l + 1];
      int total = NP * ho * wo;
      avgpool_k<<<(total + 255) / 256, 256, 0, stream>>>(pyrA[l], pyrA[l + 1], wsv[l], ho, wo, total);
      avgpool_k<<<(total + 255) / 256, 256, 0, stream>>>(pyrB[l], pyrB[l + 1], wsv[l], ho, wo, total);
    }
  }
  // init hidden state / context; zero flows
  init_k<<<(NB2 * 128 * HW + 255) / 256, 256, 0, stream>>>(FM[4], NET, X1);
  init_k<<<(NB2 * 128 * HW + 255) / 256, 256, 0, stream>>>(FM[5], ENET, X2);
  hipMemsetAsync(FLOW, 0, (size_t)NB2 * 2 * HW * 4, stream);
  hipMemsetAsync(EFLOW, 0, (size_t)NB2 * 2 * HW * 4, stream);

  float* outp = (float*)d_out;

  auto ub = [&](float* NETp, float* Xp, const float* CORRp, const float* FLOWp,
                float* DFp, bool domask) {
    // motion encoder
    conv_k<1, 1, 0, 0, 12, 4, 2, 1, false><<<dim3(6, 64, NB2), 256, 0, stream>>>(
        CORRp, nullptr, Wf[0], Bf[0], A256, 324, 0, 256, 1.f);
    conv_k<3, 3, 1, 1, 8, 4, 2, 1, false><<<dim3(6, 48, NB2), 256, 0, stream>>>(
        A256, nullptr, Wf[1], Bf[1], CFB, 256, 0, 256, 1.f);
    conv_k<7, 7, 3, 3, 2, 4, 2, 1, false><<<dim3(6, 32, NB2), 256, 0, stream>>>(
        FLOWp, nullptr, Wf[2], Bf[2], FLO, 2, 0, 128, 1.f);
    conv_k<3, 3, 1, 1, 8, 4, 2, 1, false><<<dim3(6, 16, NB2), 256, 0, stream>>>(
        FLO, nullptr, Wf[3], Bf[3], CFB, 128, 192, 256, 1.f);
    conv_k<3, 3, 1, 1, 8, 2, 2, 1, false><<<dim3(6, 63, NB2), 256, 0, stream>>>(
        CFB, nullptr, Wf[4], Bf[4], Xp, 256, 128, 256, 1.f);
    flow2x_k<<<48, 256, 0, stream>>>(FLOWp, Xp);
    // GRU horizontal (1x5)
    conv_k<1, 5, 0, 2, 8, 4, 2, 2, true><<<dim3(6, 32, NB2), 256, 0, stream>>>(
        NETp, Xp, Wf[5], Bf[5], ZB, 384, 0, 128, 1.f);
    conv_k<1, 5, 0, 2, 8, 4, 2, 2, true><<<dim3(6, 32, NB2), 256, 0, stream>>>(
        NETp, Xp, Wf[6], Bf[6], RB, 384, 0, 128, 1.f);
    gate_mul_k<<<3072, 256, 0, stream>>>(RB, NETp);
    conv_k<1, 5, 0, 2, 8, 4, 2, 3, true><<<dim3(6, 32, NB2), 256, 0, stream>>>(
        RB, Xp, Wf[7], Bf[7], QB, 384, 0, 128, 1.f);
    gru_update_k<<<3072, 256, 0, stream>>>(NETp, ZB, QB);
    // GRU vertical (5x1)
    conv_k<5, 1, 2, 0, 8, 4, 2, 2, true><<<dim3(6, 32, NB2), 256, 0, stream>>>(
        NETp, Xp, Wf[8], Bf[8], ZB, 384, 0, 128, 1.f);
    conv_k<5, 1, 2, 0, 8, 4, 2, 2, true><<<dim3(6, 32, NB2), 256, 0, stream>>>(
        NETp, Xp, Wf[9], Bf[9], RB, 384, 0, 128, 1.f);
    gate_mul_k<<<3072, 256, 0, stream>>>(RB, NETp);
    conv_k<5, 1, 2, 0, 8, 4, 2, 3, true><<<dim3(6, 32, NB2), 256, 0, stream>>>(
        RB, Xp, Wf[10], Bf[10], QB, 384, 0, 128, 1.f);
    gru_update_k<<<3072, 256, 0, stream>>>(NETp, ZB, QB);
    // flow head
    conv_k<3, 3, 1, 1, 8, 4, 2, 1, false><<<dim3(6, 64, NB2), 256, 0, stream>>>(
        NETp, nullptr, Wf[11], Bf[11], A256, 128, 0, 256, 1.f);
    conv_k<3, 3, 1, 1, 8, 2, 1, 0, false><<<dim3(12, 1, NB2), 256, 0, stream>>>(
        A256, nullptr, Wf[12], Bf[12], DFp, 256, 0, 2, 1.f);
    // mask head (net branch only)
    if (domask) {
      conv_k<3, 3, 1, 1, 8, 4, 2, 1, false><<<dim3(6, 64, NB2), 256, 0, stream>>>(
          NETp, nullptr, Wf[13], Bf[13], A256, 128, 0, 256, 1.f);
      conv_k<1, 1, 0, 0, 8, 4, 2, 0, false><<<dim3(6, 144, NB2), 256, 0, stream>>>(
          A256, nullptr, Wf[14], Bf[14], MASK, 256, 0, 576, 0.25f);
    }
  };

  for (int it = 0; it < ITERS; ++it) {
    lookup_k<<<dim3(96, 81), 256, 0, stream>>>(pyrA[0], pyrA[1], pyrA[2], pyrA[3], FLOW, CORR);
    lookup_k<<<dim3(96, 81), 256, 0, stream>>>(pyrB[0], pyrB[1], pyrB[2], pyrB[3], EFLOW, ECORR);
    ub(NET, X1, CORR, FLOW, DF, true);
    ub(ENET, X2, ECORR, EFLOW, EDF, false);
    flow_update_k<<<48, 256, 0, stream>>>(FLOW, EFLOW, DF, EDF);
    upsample_k<<<dim3(2, 8, 96), 256, 0, stream>>>(FLOW, MASK,
                                                   outp + (size_t)it * (NB2 * 2 * 384 * 512));
  }
}

// Round 3
// 76325.037 us; speedup vs baseline: 1.3156x; 1.3156x over previous
//
#include <hip/hip_runtime.h>
#include <stdint.h>

typedef unsigned short ushort_t;

#define DEVINL static __device__ __forceinline__

DEVINL float bits2f(unsigned int b) { union { unsigned int i; float f; } v; v.i = b; return v.f; }
DEVINL float bf2f(ushort_t u) { return bits2f(((unsigned int)u) << 16); }
DEVINL ushort_t f2bf(float x) {
  union { float f; unsigned int i; } v; v.f = x;
  return (ushort_t)((v.i + 0x7FFFu + ((v.i >> 16) & 1u)) >> 16);
}

constexpr int NB2 = 2;
constexpr int HH = 48, WW = 64, HW = 3072;
constexpr int NP = NB2 * HW;   // 6144 pyramid rows
constexpr int CFEAT = 256;
constexpr int ITERS = 12;

// ---------------------------------------------------------------------------
// dtype detector: bf16-interpret first 4096 halfwords of fmap1. flag=1 -> f32.
// ---------------------------------------------------------------------------
__global__ __launch_bounds__(256) void detect_k(const ushort_t* __restrict__ src,
                                                int* __restrict__ flag) {
  const int t = threadIdx.x;
  int bad = 0;
  for (int i = t; i < 4096; i += 256) {
    const float v = bf2f(src[i]);
    if (!(fabsf(v) < 1e30f)) bad = 1;
  }
  __shared__ int s;
  if (t == 0) s = 0;
  __syncthreads();
  if (bad) atomicOr(&s, 1);
  __syncthreads();
  if (t == 0) *flag = s;
}

// ---------------------------------------------------------------------------
// convert all 36 input tensors to f32 workspace copies (dual dtype mode)
// ---------------------------------------------------------------------------
struct CvtArgs {
  const void* src[36];
  float* dst[36];
  int n[36];
};
__global__ __launch_bounds__(256) void cvt_all_k(CvtArgs a, const int* __restrict__ flag) {
  const bool isf32 = (*flag != 0);
  const int stride = gridDim.x * 256;
  const int t0 = blockIdx.x * 256 + threadIdx.x;
  for (int s = 0; s < 36; ++s) {
    float* dst = a.dst[s];
    const int n = a.n[s];
    if (isf32) {
      const float* src = (const float*)a.src[s];
      for (int i = t0; i < n; i += stride) dst[i] = src[i];
    } else {
      const ushort_t* src = (const ushort_t*)a.src[s];
      for (int i = t0; i < n; i += stride) dst[i] = bf2f(src[i]);
    }
  }
}

// ---------------------------------------------------------------------------
// Correlation GEMM (unchanged from passing round)
// ---------------------------------------------------------------------------
__global__ __launch_bounds__(256) void corr_gemm_k(const float* __restrict__ f1,
                                                   const float* __restrict__ f2,
                                                   ushort_t* __restrict__ out) {
  const int nb = blockIdx.z;
  const int m0 = blockIdx.x * 64, n0 = blockIdx.y * 64;
  const int tid = threadIdx.x;
  const int tx = tid & 15, ty = tid >> 4;
  __shared__ __align__(16) float As[16][64];
  __shared__ __align__(16) float Bs[16][64];
  const float* pa = f1 + (size_t)nb * CFEAT * HW;
  const float* pb = f2 + (size_t)nb * CFEAT * HW;
  const int lr = tid >> 4;
  const int lc = (tid & 15) * 4;
  float acc[4][4];
#pragma unroll
  for (int i = 0; i < 4; ++i)
#pragma unroll
    for (int j = 0; j < 4; ++j) acc[i][j] = 0.f;

  for (int k0 = 0; k0 < CFEAT; k0 += 16) {
    const float4 va = *(const float4*)(pa + (size_t)(k0 + lr) * HW + m0 + lc);
    const float4 vb = *(const float4*)(pb + (size_t)(k0 + lr) * HW + n0 + lc);
    __syncthreads();
    As[lr][lc + 0] = va.x;
    As[lr][lc + 1] = va.y;
    As[lr][lc + 2] = va.z;
    As[lr][lc + 3] = va.w;
    Bs[lr][lc + 0] = vb.x;
    Bs[lr][lc + 1] = vb.y;
    Bs[lr][lc + 2] = vb.z;
    Bs[lr][lc + 3] = vb.w;
    __syncthreads();
#pragma unroll
    for (int kk = 0; kk < 16; ++kk) {
      const float4 a = *(const float4*)&As[kk][ty * 4];
      const float4 b = *(const float4*)&Bs[kk][tx * 4];
      acc[0][0] = fmaf(a.x, b.x, acc[0][0]);
      acc[0][1] = fmaf(a.x, b.y, acc[0][1]);
      acc[0][2] = fmaf(a.x, b.z, acc[0][2]);
      acc[0][3] = fmaf(a.x, b.w, acc[0][3]);
      acc[1][0] = fmaf(a.y, b.x, acc[1][0]);
      acc[1][1] = fmaf(a.y, b.y, acc[1][1]);
      acc[1][2] = fmaf(a.y, b.z, acc[1][2]);
      acc[1][3] = fmaf(a.y, b.w, acc[1][3]);
      acc[2][0] = fmaf(a.z, b.x, acc[2][0]);
      acc[2][1] = fmaf(a.z, b.y, acc[2][1]);
      acc[2][2] = fmaf(a.z, b.z, acc[2][2]);
      acc[2][3] = fmaf(a.z, b.w, acc[2][3]);
      acc[3][0] = fmaf(a.w, b.x, acc[3][0]);
      acc[3][1] = fmaf(a.w, b.y, acc[3][1]);
      acc[3][2] = fmaf(a.w, b.z, acc[3][2]);
      acc[3][3] = fmaf(a.w, b.w, acc[3][3]);
    }
  }
#pragma unroll
  for (int ii = 0; ii < 4; ++ii)
#pragma unroll
    for (int jj = 0; jj < 4; ++jj) {
      const int mi = m0 + ty * 4 + ii;
      const int nj = n0 + tx * 4 + jj;
      out[((size_t)nb * HW + mi) * HW + nj] = f2bf(acc[ii][jj] * 0.0625f);
    }
}

__global__ __launch_bounds__(256) void avgpool_k(const ushort_t* __restrict__ in,
                                                 ushort_t* __restrict__ out,
                                                 int wi, int ho, int wo, int total) {
  int idx = blockIdx.x * 256 + threadIdx.x;
  if (idx >= total) return;
  int pw = ho * wo;
  int p = idx / pw;
  int r = idx - p * pw;
  int y = r / wo;
  int x = r - y * wo;
  const ushort_t* src = in + (size_t)p * (4 * pw) + (2 * y) * wi + 2 * x;
  float v = (bf2f(src[0]) + bf2f(src[1]) + bf2f(src[wi]) + bf2f(src[wi + 1])) * 0.25f;
  out[idx] = f2bf(v);
}

// ---------------------------------------------------------------------------
// Correlation lookup (unchanged)
// ---------------------------------------------------------------------------
__global__ __launch_bounds__(256) void lookup_k(
    const ushort_t* __restrict__ l0, const ushort_t* __restrict__ l1,
    const ushort_t* __restrict__ l2, const ushort_t* __restrict__ l3,
    const float* __restrict__ flow, float* __restrict__ out) {
  const int t = threadIdx.x;
  const int p = blockIdx.x * 64 + (t & 63);
  const int c = blockIdx.y * 4 + (t >> 6);
  const int nb = p / HW;
  const int rem = p - nb * HW;
  const int yy = rem >> 6, xx = rem & 63;
  const float fx = flow[((size_t)(nb * 2 + 0)) * HW + rem];
  const float fy = flow[((size_t)(nb * 2 + 1)) * HW + rem];
  const int l = c / 81;
  const int k = c - l * 81;
  const float dx = (float)(k / 9) - 4.f;
  const float dy = (float)(k - (k / 9) * 9) - 4.f;
  const int hl = HH >> l, wl = WW >> l;
  const ushort_t* base = (l == 0) ? l0 : (l == 1) ? l1 : (l == 2) ? l2 : l3;
  const ushort_t* img = base + (size_t)p * (hl * wl);
  const float s = 1.f / (float)(1 << l);
  const float xl = ((float)xx + fx) * s + dx;
  const float yl = ((float)yy + fy) * s + dy;
  const float x0f = floorf(xl), y0f = floorf(yl);
  float acc = 0.f;
#pragma unroll
  for (int dy2 = 0; dy2 < 2; ++dy2) {
#pragma unroll
    for (int dx2 = 0; dx2 < 2; ++dx2) {
      const float xi = x0f + dx2, yi = y0f + dy2;
      if (xi >= 0.f && xi <= (float)(wl - 1) && yi >= 0.f && yi <= (float)(hl - 1)) {
        const float wv = (1.f - fabsf(xl - xi)) * (1.f - fabsf(yl - yi));
        acc += wv * bf2f(img[(int)yi * wl + (int)xi]);
      }
    }
  }
  out[((size_t)(nb * 324 + c)) * HW + rem] = acc;
}

// ---------------------------------------------------------------------------
// Direct conv v2: weights staged in LDS (broadcast ds_read_b128/b64), fused
// epilogues. Input layout (NB2, CI_TOT, 48, 64) fp32; conv consumes CI chans
// starting at ci_base. MODE: 0 plain; 1 split [xa 128ch | xb 256ch];
// 2 split with xa-part multiplied by r (= zb chans 128..256).
// UPD epilogue: y = (1-z)*old + z*act(acc+bias), z = zb[co], old = xg[co].
// ACT: 0 none, 1 relu, 2 sigmoid, 3 tanh. out *= scale before UPD.
// ---------------------------------------------------------------------------
template <int KH, int KW, int PH, int PW, int CSTEP, int OCPT, int PXPT, int ACT,
          int MODE, bool UPD>
__global__ __launch_bounds__(256) void conv_k(
    const float* __restrict__ xa, const float* __restrict__ xb,
    const float* __restrict__ xg, const float* __restrict__ zb,
    const float* __restrict__ wgt, const float* __restrict__ bias,
    float* __restrict__ y, int CI, int ci_base, int CI_TOT,
    int co_base, int CO_TOT, float scale) {
  constexpr int ROWS = 4 * PXPT;
  constexpr int TR = ROWS + 2 * PH;
  constexpr int TC = 64 + 2 * PW;
  constexpr int TSZ = CSTEP * TR * TC;
  constexpr int KHKW = KH * KW;
  constexpr int WLSZ = CSTEP * KHKW * OCPT;
  __shared__ __align__(16) float tile[TSZ];
  __shared__ __align__(16) float wlds[WLSZ];
  const int tid = threadIdx.x;
  const int nb = blockIdx.z;
  const int y0 = blockIdx.x * ROWS;
  const int co0 = blockIdx.y * OCPT;
  const int rxt = tid & 63;
  const int ryt = tid >> 6;
  float acc[OCPT][PXPT];
#pragma unroll
  for (int k = 0; k < OCPT; ++k)
#pragma unroll
    for (int px = 0; px < PXPT; ++px) acc[k][px] = 0.f;

  for (int c0 = 0; c0 < CI; c0 += CSTEP) {
    __syncthreads();
    // ---- stage input tile ----
    for (int e = tid; e < TSZ; e += 256) {
      const int cl = e / (TR * TC);
      const int r = e - cl * (TR * TC);
      const int ry = r / TC;
      const int rx = r - ry * TC;
      const int gy = y0 - PH + ry;
      const int gx = rx - PW;
      float v = 0.f;
      if ((unsigned)gy < 48u && (unsigned)gx < 64u) {
        const int c = c0 + cl;
        const int pix = gy * 64 + gx;
        if (MODE == 0) {
          v = xa[((size_t)(nb * CI_TOT + ci_base + c)) * HW + pix];
        } else {
          if (c < 128) {
            v = xa[((size_t)(nb * 128 + c)) * HW + pix];
            if (MODE == 2) v *= zb[((size_t)(nb * 256 + 128 + c)) * HW + pix];
          } else {
            v = xb[((size_t)(nb * 256 + (c - 128))) * HW + pix];
          }
        }
      }
      tile[e] = v;
    }
    // ---- stage weights: wlds[(cl*KHKW + t)*OCPT + k] ----
    for (int e = tid; e < WLSZ; e += 256) {
      const int k = e & (OCPT - 1);
      const int rest = e / OCPT;
      const int t = rest % KHKW;
      const int cl = rest / KHKW;
      wlds[e] = wgt[((size_t)(co0 + k) * CI + (c0 + cl)) * KHKW + t];
    }
    __syncthreads();
    // ---- compute ----
#pragma unroll
    for (int cl = 0; cl < CSTEP; ++cl) {
#pragma unroll
      for (int kh = 0; kh < KH; ++kh) {
#pragma unroll
        for (int kw = 0; kw < KW; ++kw) {
          const int widx = (cl * KHKW + kh * KW + kw) * OCPT;
          float wv0, wv1, wv2 = 0.f, wv3 = 0.f;
          if (OCPT == 4) {
            const float4 w4 = *(const float4*)&wlds[widx];
            wv0 = w4.x; wv1 = w4.y; wv2 = w4.z; wv3 = w4.w;
          } else {
            const float2 w2 = *(const float2*)&wlds[widx];
            wv0 = w2.x; wv1 = w2.y;
          }
#pragma unroll
          for (int px = 0; px < PXPT; ++px) {
            const float v = tile[(cl * TR + ryt + px * 4 + kh) * TC + rxt + kw];
            acc[0][px] = fmaf(wv0, v, acc[0][px]);
            acc[1][px] = fmaf(wv1, v, acc[1][px]);
            if (OCPT == 4) {
              acc[2][px] = fmaf(wv2, v, acc[2][px]);
              acc[3][px] = fmaf(wv3, v, acc[3][px]);
            }
          }
        }
      }
    }
  }
  // ---- epilogue ----
#pragma unroll
  for (int k = 0; k < OCPT; ++k) {
    const float b = bias[co0 + k];
#pragma unroll
    for (int px = 0; px < PXPT; ++px) {
      float v = acc[k][px] + b;
      if (ACT == 1) v = fmaxf(v, 0.f);
      if (ACT == 2) v = 1.f / (1.f + __expf(-v));
      if (ACT == 3) v = tanhf(v);
      v *= scale;
      const int pix = (y0 + ryt + px * 4) * 64 + rxt;
      if (UPD) {
        const int co = co0 + k;
        const float z = zb[((size_t)(nb * 256 + co)) * HW + pix];
        const float old = xg[((size_t)(nb * 128 + co)) * HW + pix];
        v = (1.f - z) * old + z * v;
      }
      y[((size_t)(nb * CO_TOT + co_base + co0 + k)) * HW + pix] = v;
    }
  }
}

// ---------------------------------------------------------------------------
// small elementwise kernels
// ---------------------------------------------------------------------------
__global__ __launch_bounds__(256) void init_k(const float* __restrict__ cnet,
                                              float* __restrict__ net, float* __restrict__ X) {
  int idx = blockIdx.x * 256 + threadIdx.x;  // NB2*128*HW
  if (idx >= NB2 * 128 * HW) return;
  int nb = idx / (128 * HW);
  int r = idx - nb * 128 * HW;
  int c = r / HW;
  int p = r - c * HW;
  float vn = cnet[((size_t)(nb * 256 + c)) * HW + p];
  float vi = cnet[((size_t)(nb * 256 + 128 + c)) * HW + p];
  net[idx] = tanhf(vn);
  X[((size_t)(nb * 256 + c)) * HW + p] = fmaxf(vi, 0.f);
}

__global__ __launch_bounds__(256) void flow2x_k(const float* __restrict__ flow,
                                                float* __restrict__ X) {
  int i = blockIdx.x * 256 + threadIdx.x;  // NB2*2*HW
  if (i >= NB2 * 2 * HW) return;
  int nb = i / (2 * HW);
  int r = i - nb * 2 * HW;
  int ch = r / HW;
  int p = r - ch * HW;
  X[((size_t)(nb * 256 + 254 + ch)) * HW + p] = flow[i];
}

__global__ __launch_bounds__(256) void flow_update_k(float* __restrict__ flow,
                                                     float* __restrict__ eflow,
                                                     const float* __restrict__ df,
                                                     const float* __restrict__ edf) {
  int i = blockIdx.x * 256 + threadIdx.x;
  if (i < NB2 * 2 * HW) {
    float e = edf[i];
    flow[i] += df[i] + e;
    eflow[i] += e;
  }
}

__global__ __launch_bounds__(256) void upsample_k(const float* __restrict__ flow,
                                                  const float* __restrict__ mask,
                                                  float* __restrict__ out) {
  const int j = threadIdx.x & 7;
  const int xh = threadIdx.x >> 3;
  const int x = blockIdx.x * 32 + xh;
  const int i = blockIdx.y;
  const int nz = blockIdx.z;
  const int nb = nz / 48, yy = nz - nb * 48;
  const int rem = yy * 64 + x;
  float m[9];
  float mx = -1e30f;
#pragma unroll
  for (int k = 0; k < 9; ++k) {
    m[k] = mask[((size_t)(nb * 576 + k * 64 + i * 8 + j)) * HW + rem];
    mx = fmaxf(mx, m[k]);
  }
  float sum = 0.f;
#pragma unroll
  for (int k = 0; k < 9; ++k) {
    m[k] = __expf(m[k] - mx);
    sum += m[k];
  }
  const float inv = 8.f / sum;
#pragma unroll
  for (int ch = 0; ch < 2; ++ch) {
    float acc = 0.f;
#pragma unroll
    for (int k = 0; k < 9; ++k) {
      const int gy = yy + k / 3 - 1;
      const int gx = x + (k - (k / 3) * 3) - 1;
      float f = 0.f;
      if ((unsigned)gy < 48u && (unsigned)gx < 64u)
        f = flow[((size_t)(nb * 2 + ch)) * HW + gy * 64 + gx];
      acc = fmaf(m[k], f, acc);
    }
    out[(((size_t)(nb * 2 + ch)) * 384 + (yy * 8 + i)) * 512 + x * 8 + j] = acc * inv;
  }
}

// ---------------------------------------------------------------------------
// host orchestration
// ---------------------------------------------------------------------------
extern "C" void kernel_launch(void* const* d_in, const int* in_sizes, int n_in,
                              void* d_out, int out_size, void* d_ws, size_t ws_size,
                              hipStream_t stream) {
  (void)in_sizes; (void)n_in; (void)out_size;

  size_t off = 0;
  char* base = (char*)d_ws;
  auto take = [&](size_t nbytes) -> void* {
    void* p = base + off;
    off += (nbytes + 255) & ~(size_t)255;
    return p;
  };
  ushort_t* pyrA[4];
  ushort_t* pyrB[4];
  const int lsz[4] = {3072, 768, 192, 48};
  for (int l = 0; l < 4; ++l) pyrA[l] = (ushort_t*)take((size_t)NP * lsz[l] * 2);
  for (int l = 0; l < 4; ++l) pyrB[l] = (ushort_t*)take((size_t)NP * lsz[l] * 2);
  float* FM[6];
  for (int s = 0; s < 6; ++s) FM[s] = (float*)take((size_t)NB2 * 256 * HW * 4);
  float* CORR = (float*)take((size_t)NB2 * 324 * HW * 4);
  float* ECORR = (float*)take((size_t)NB2 * 324 * HW * 4);
  float* NET = (float*)take((size_t)NB2 * 128 * HW * 4);
  float* ENET = (float*)take((size_t)NB2 * 128 * HW * 4);
  float* NETB = (float*)take((size_t)NB2 * 128 * HW * 4);  // GRU ping-pong
  float* X1 = (float*)take((size_t)NB2 * 256 * HW * 4);
  float* X2 = (float*)take((size_t)NB2 * 256 * HW * 4);
  float* FLOW = (float*)take((size_t)NB2 * 2 * HW * 4);
  float* EFLOW = (float*)take((size_t)NB2 * 2 * HW * 4);
  float* DF = (float*)take((size_t)NB2 * 2 * HW * 4);
  float* EDF = (float*)take((size_t)NB2 * 2 * HW * 4);
  float* FLO = (float*)take((size_t)NB2 * 128 * HW * 4);
  float* ZRB = (float*)take((size_t)NB2 * 256 * HW * 4);   // z | r
  float* A256 = (float*)take((size_t)NB2 * 256 * HW * 4);
  float* CFB = (float*)take((size_t)NB2 * 256 * HW * 4);
  float* A512 = (float*)take((size_t)NB2 * 512 * HW * 4);  // fh1 | mk1
  float* MASK = (float*)take((size_t)NB2 * 576 * HW * 4);

  static const int WSZ[15] = {82944, 442368, 12544, 73728, 290304,
                              245760, 245760, 245760, 245760, 245760, 245760,
                              294912, 4608, 294912, 147456};
  static const int BSZ[15] = {256, 192, 128, 64, 126, 128, 128, 128,
                              128, 128, 128, 256, 2, 256, 576};
  float* Wf[15];
  float* Bf[15];
  // contiguity-aware allocation: (5,6), (8,9), (11,13) stacked pairs
  for (int s = 0; s < 5; ++s) Wf[s] = (float*)take((size_t)WSZ[s] * 4);
  Wf[5] = (float*)take((size_t)2 * 245760 * 4); Wf[6] = Wf[5] + 245760;
  Wf[7] = (float*)take((size_t)245760 * 4);
  Wf[8] = (float*)take((size_t)2 * 245760 * 4); Wf[9] = Wf[8] + 245760;
  Wf[10] = (float*)take((size_t)245760 * 4);
  Wf[11] = (float*)take((size_t)2 * 294912 * 4); Wf[13] = Wf[11] + 294912;
  Wf[12] = (float*)take((size_t)4608 * 4);
  Wf[14] = (float*)take((size_t)147456 * 4);
  for (int s = 0; s < 5; ++s) Bf[s] = (float*)take((size_t)BSZ[s] * 4);
  Bf[5] = (float*)take((size_t)2 * 128 * 4); Bf[6] = Bf[5] + 128;
  Bf[7] = (float*)take((size_t)128 * 4);
  Bf[8] = (float*)take((size_t)2 * 128 * 4); Bf[9] = Bf[8] + 128;
  Bf[10] = (float*)take((size_t)128 * 4);
  Bf[11] = (float*)take((size_t)2 * 256 * 4); Bf[13] = Bf[11] + 256;
  Bf[12] = (float*)take((size_t)2 * 4);
  Bf[14] = (float*)take((size_t)576 * 4);
  int* FLAG = (int*)take(256);

  if (off > ws_size) return;

  detect_k<<<1, 256, 0, stream>>>((const ushort_t*)d_in[0], FLAG);
  CvtArgs ca;
  for (int s = 0; s < 6; ++s) {
    ca.src[s] = d_in[s];
    ca.dst[s] = FM[s];
    ca.n[s] = NB2 * 256 * HW;
  }
  for (int s = 0; s < 15; ++s) {
    ca.src[6 + s] = d_in[6 + 2 * s];
    ca.dst[6 + s] = Wf[s];
    ca.n[6 + s] = WSZ[s];
    ca.src[21 + s] = d_in[7 + 2 * s];
    ca.dst[21 + s] = Bf[s];
    ca.n[21 + s] = BSZ[s];
  }
  cvt_all_k<<<1024, 256, 0, stream>>>(ca, FLAG);

  corr_gemm_k<<<dim3(48, 48, NB2), 256, 0, stream>>>(FM[0], FM[1], pyrA[0]);
  corr_gemm_k<<<dim3(48, 48, NB2), 256, 0, stream>>>(FM[2], FM[3], pyrB[0]);
  {
    const int wsv[4] = {64, 32, 16, 8};
    const int hsv[4] = {48, 24, 12, 6};
    for (int l = 0; l < 3; ++l) {
      int ho = hsv[l + 1], wo = wsv[l + 1];
      int total = NP * ho * wo;
      avgpool_k<<<(total + 255) / 256, 256, 0, stream>>>(pyrA[l], pyrA[l + 1], wsv[l], ho, wo, total);
      avgpool_k<<<(total + 255) / 256, 256, 0, stream>>>(pyrB[l], pyrB[l + 1], wsv[l], ho, wo, total);
    }
  }
  init_k<<<(NB2 * 128 * HW + 255) / 256, 256, 0, stream>>>(FM[4], NET, X1);
  init_k<<<(NB2 * 128 * HW + 255) / 256, 256, 0, stream>>>(FM[5], ENET, X2);
  hipMemsetAsync(FLOW, 0, (size_t)NB2 * 2 * HW * 4, stream);
  hipMemsetAsync(EFLOW, 0, (size_t)NB2 * 2 * HW * 4, stream);

  float* outp = (float*)d_out;
  const float* NUL = nullptr;

  auto ub = [&](float* NETp, float* Xp, const float* CORRp, const float* FLOWp,
                float* DFp, bool domask) {
    // motion encoder
    conv_k<1, 1, 0, 0, 12, 4, 2, 1, 0, false><<<dim3(6, 64, NB2), 256, 0, stream>>>(
        CORRp, NUL, NUL, NUL, Wf[0], Bf[0], A256, 324, 0, 324, 0, 256, 1.f);
    conv_k<3, 3, 1, 1, 8, 4, 2, 1, 0, false><<<dim3(6, 48, NB2), 256, 0, stream>>>(
        A256, NUL, NUL, NUL, Wf[1], Bf[1], CFB, 256, 0, 256, 0, 256, 1.f);
    conv_k<7, 7, 3, 3, 2, 4, 2, 1, 0, false><<<dim3(6, 32, NB2), 256, 0, stream>>>(
        FLOWp, NUL, NUL, NUL, Wf[2], Bf[2], FLO, 2, 0, 2, 0, 128, 1.f);
    conv_k<3, 3, 1, 1, 8, 4, 2, 1, 0, false><<<dim3(6, 16, NB2), 256, 0, stream>>>(
        FLO, NUL, NUL, NUL, Wf[3], Bf[3], CFB, 128, 0, 128, 192, 256, 1.f);
    conv_k<3, 3, 1, 1, 8, 2, 2, 1, 0, false><<<dim3(6, 63, NB2), 256, 0, stream>>>(
        CFB, NUL, NUL, NUL, Wf[4], Bf[4], Xp, 256, 0, 256, 128, 256, 1.f);
    flow2x_k<<<48, 256, 0, stream>>>(FLOWp, Xp);
    // GRU horizontal (1x5): fused z|r, then q with gate-mul staging + update epi
    conv_k<1, 5, 0, 2, 8, 4, 2, 2, 1, false><<<dim3(6, 64, NB2), 256, 0, stream>>>(
        NETp, Xp, NUL, NUL, Wf[5], Bf[5], ZRB, 384, 0, 0, 0, 256, 1.f);
    conv_k<1, 5, 0, 2, 8, 4, 2, 3, 2, true><<<dim3(6, 32, NB2), 256, 0, stream>>>(
        NETp, Xp, NETp, ZRB, Wf[7], Bf[7], NETB, 384, 0, 0, 0, 128, 1.f);
    // GRU vertical (5x1)
    conv_k<5, 1, 2, 0, 8, 4, 2, 2, 1, false><<<dim3(6, 64, NB2), 256, 0, stream>>>(
        NETB, Xp, NUL, NUL, Wf[8], Bf[8], ZRB, 384, 0, 0, 0, 256, 1.f);
    conv_k<5, 1, 2, 0, 8, 4, 2, 3, 2, true><<<dim3(6, 32, NB2), 256, 0, stream>>>(
        NETB, Xp, NETB, ZRB, Wf[10], Bf[10], NETp, 384, 0, 0, 0, 128, 1.f);
    // heads: fh1 (+mk1 when domask) fused into A512
    conv_k<3, 3, 1, 1, 8, 4, 2, 1, 0, false><<<dim3(6, domask ? 128 : 64, NB2), 256, 0, stream>>>(
        NETp, NUL, NUL, NUL, Wf[11], Bf[11], A512, 128, 0, 128, 0, 512, 1.f);
    conv_k<3, 3, 1, 1, 8, 2, 1, 0, 0, false><<<dim3(12, 1, NB2), 256, 0, stream>>>(
        A512, NUL, NUL, NUL, Wf[12], Bf[12], DFp, 256, 0, 512, 0, 2, 1.f);
    if (domask) {
      conv_k<1, 1, 0, 0, 8, 4, 2, 0, 0, false><<<dim3(6, 144, NB2), 256, 0, stream>>>(
          A512, NUL, NUL, NUL, Wf[14], Bf[14], MASK, 256, 256, 512, 0, 576, 0.25f);
    }
  };

  for (int it = 0; it < ITERS; ++it) {
    lookup_k<<<dim3(96, 81), 256, 0, stream>>>(pyrA[0], pyrA[1], pyrA[2], pyrA[3], FLOW, CORR);
    lookup_k<<<dim3(96, 81), 256, 0, stream>>>(pyrB[0], pyrB[1], pyrB[2], pyrB[3], EFLOW, ECORR);
    ub(NET, X1, CORR, FLOW, DF, true);
    ub(ENET, X2, ECORR, EFLOW, EDF, false);
    flow_update_k<<<48, 256, 0, stream>>>(FLOW, EFLOW, DF, EDF);
    upsample_k<<<dim3(2, 8, 96), 256, 0, stream>>>(FLOW, MASK,
                                                   outp + (size_t)it * (NB2 * 2 * 384 * 512));
  }
}

// Round 4
// 7928.017 us; speedup vs baseline: 12.6656x; 9.6273x over previous
//
#include <hip/hip_runtime.h>
#include <stdint.h>

typedef unsigned short ushort_t;
using bfx8 = __attribute__((ext_vector_type(8))) short;
using f32x4 = __attribute__((ext_vector_type(4))) float;

#define DEVINL static __device__ __forceinline__

DEVINL float bits2f(unsigned int b) { union { unsigned int i; float f; } v; v.i = b; return v.f; }
DEVINL float bf2f(ushort_t u) { return bits2f(((unsigned int)u) << 16); }
DEVINL ushort_t f2bf(float x) {
  union { float f; unsigned int i; } v; v.f = x;
  return (ushort_t)((v.i + 0x7FFFu + ((v.i >> 16) & 1u)) >> 16);
}
DEVINL unsigned int mulbf2(unsigned int a, unsigned int r) {
  float a0 = bits2f(a << 16), a1 = bits2f(a & 0xFFFF0000u);
  float r0 = bits2f(r << 16), r1 = bits2f(r & 0xFFFF0000u);
  return (unsigned int)f2bf(a0 * r0) | ((unsigned int)f2bf(a1 * r1) << 16);
}

constexpr int NB2 = 2;
constexpr int HH = 48, WW = 64, HW = 3072;
constexpr int NP = NB2 * HW;
constexpr int CFEAT = 256;
constexpr int ITERS = 12;
constexpr int CCP = 72;  // 64 channels + 8 pad (bank-conflict break)

// ---------------------------------------------------------------------------
// dtype detector + unified f32 conversion (inputs may be bf16 or f32)
// ---------------------------------------------------------------------------
__global__ __launch_bounds__(256) void detect_k(const ushort_t* __restrict__ src,
                                                int* __restrict__ flag) {
  const int t = threadIdx.x;
  int bad = 0;
  for (int i = t; i < 4096; i += 256) {
    const float v = bf2f(src[i]);
    if (!(fabsf(v) < 1e30f)) bad = 1;
  }
  __shared__ int s;
  if (t == 0) s = 0;
  __syncthreads();
  if (bad) atomicOr(&s, 1);
  __syncthreads();
  if (t == 0) *flag = s;
}

struct CvtArgs {
  const void* src[36];
  float* dst[36];
  int n[36];
};
__global__ __launch_bounds__(256) void cvt_all_k(CvtArgs a, const int* __restrict__ flag) {
  const bool isf32 = (*flag != 0);
  const int stride = gridDim.x * 256;
  const int t0 = blockIdx.x * 256 + threadIdx.x;
  for (int s = 0; s < 36; ++s) {
    float* dst = a.dst[s];
    const int n = a.n[s];
    if (isf32) {
      const float* src = (const float*)a.src[s];
      for (int i = t0; i < n; i += stride) dst[i] = src[i];
    } else {
      const ushort_t* src = (const ushort_t*)a.src[s];
      for (int i = t0; i < n; i += stride) dst[i] = bf2f(src[i]);
    }
  }
}

// ---------------------------------------------------------------------------
// weight pack: f32 (CO, CI, KH, KW) -> B-fragment order bf16
// dst[((b*KST + s)*64 + l)*8 + j] = W[n=b*16+(l&15)][k], k order:
// chunk(64ch)-major, tap, half(32), quad(8), j. Zero-pad n>=CO or ci>=CI.
// ---------------------------------------------------------------------------
__global__ __launch_bounds__(256) void pack_k(const float* __restrict__ src,
                                              ushort_t* __restrict__ dst,
                                              int CO, int CI_real, int KHKW,
                                              int NCHUNK, int total) {
  int idx = blockIdx.x * 256 + threadIdx.x;
  if (idx >= total) return;
  const int KST = NCHUNK * KHKW * 2;
  const int j = idx & 7;
  const int l = (idx >> 3) & 63;
  const int s = (idx >> 9) % KST;
  const int b = idx / (512 * KST);
  const int chunk = s / (KHKW * 2);
  const int r = s - chunk * KHKW * 2;
  const int t = r >> 1;
  const int half = r & 1;
  const int ci = chunk * 64 + half * 32 + ((l >> 4) & 3) * 8 + j;
  const int n = b * 16 + (l & 15);
  float v = 0.f;
  if (n < CO && ci < CI_real) v = src[((size_t)n * CI_real + ci) * KHKW + t];
  dst[idx] = f2bf(v);
}

// ---------------------------------------------------------------------------
// Correlation GEMM (f32 SIMT, unchanged) + avg-pool
// ---------------------------------------------------------------------------
__global__ __launch_bounds__(256) void corr_gemm_k(const float* __restrict__ f1,
                                                   const float* __restrict__ f2,
                                                   ushort_t* __restrict__ out) {
  const int nb = blockIdx.z;
  const int m0 = blockIdx.x * 64, n0 = blockIdx.y * 64;
  const int tid = threadIdx.x;
  const int tx = tid & 15, ty = tid >> 4;
  __shared__ __align__(16) float As[16][64];
  __shared__ __align__(16) float Bs[16][64];
  const float* pa = f1 + (size_t)nb * CFEAT * HW;
  const float* pb = f2 + (size_t)nb * CFEAT * HW;
  const int lr = tid >> 4;
  const int lc = (tid & 15) * 4;
  float acc[4][4];
#pragma unroll
  for (int i = 0; i < 4; ++i)
#pragma unroll
    for (int j = 0; j < 4; ++j) acc[i][j] = 0.f;

  for (int k0 = 0; k0 < CFEAT; k0 += 16) {
    const float4 va = *(const float4*)(pa + (size_t)(k0 + lr) * HW + m0 + lc);
    const float4 vb = *(const float4*)(pb + (size_t)(k0 + lr) * HW + n0 + lc);
    __syncthreads();
    As[lr][lc + 0] = va.x; As[lr][lc + 1] = va.y; As[lr][lc + 2] = va.z; As[lr][lc + 3] = va.w;
    Bs[lr][lc + 0] = vb.x; Bs[lr][lc + 1] = vb.y; Bs[lr][lc + 2] = vb.z; Bs[lr][lc + 3] = vb.w;
    __syncthreads();
#pragma unroll
    for (int kk = 0; kk < 16; ++kk) {
      const float4 a = *(const float4*)&As[kk][ty * 4];
      const float4 b = *(const float4*)&Bs[kk][tx * 4];
      acc[0][0] = fmaf(a.x, b.x, acc[0][0]); acc[0][1] = fmaf(a.x, b.y, acc[0][1]);
      acc[0][2] = fmaf(a.x, b.z, acc[0][2]); acc[0][3] = fmaf(a.x, b.w, acc[0][3]);
      acc[1][0] = fmaf(a.y, b.x, acc[1][0]); acc[1][1] = fmaf(a.y, b.y, acc[1][1]);
      acc[1][2] = fmaf(a.y, b.z, acc[1][2]); acc[1][3] = fmaf(a.y, b.w, acc[1][3]);
      acc[2][0] = fmaf(a.z, b.x, acc[2][0]); acc[2][1] = fmaf(a.z, b.y, acc[2][1]);
      acc[2][2] = fmaf(a.z, b.z, acc[2][2]); acc[2][3] = fmaf(a.z, b.w, acc[2][3]);
      acc[3][0] = fmaf(a.w, b.x, acc[3][0]); acc[3][1] = fmaf(a.w, b.y, acc[3][1]);
      acc[3][2] = fmaf(a.w, b.z, acc[3][2]); acc[3][3] = fmaf(a.w, b.w, acc[3][3]);
    }
  }
#pragma unroll
  for (int ii = 0; ii < 4; ++ii)
#pragma unroll
    for (int jj = 0; jj < 4; ++jj) {
      const int mi = m0 + ty * 4 + ii;
      const int nj = n0 + tx * 4 + jj;
      out[((size_t)nb * HW + mi) * HW + nj] = f2bf(acc[ii][jj] * 0.0625f);
    }
}

__global__ __launch_bounds__(256) void avgpool_k(const ushort_t* __restrict__ in,
                                                 ushort_t* __restrict__ out,
                                                 int wi, int ho, int wo, int total) {
  int idx = blockIdx.x * 256 + threadIdx.x;
  if (idx >= total) return;
  int pw = ho * wo;
  int p = idx / pw;
  int r = idx - p * pw;
  int y = r / wo;
  int x = r - y * wo;
  const ushort_t* src = in + (size_t)p * (4 * pw) + (2 * y) * wi + 2 * x;
  float v = (bf2f(src[0]) + bf2f(src[1]) + bf2f(src[wi]) + bf2f(src[wi + 1])) * 0.25f;
  out[idx] = f2bf(v);
}

// ---------------------------------------------------------------------------
// Correlation lookup -> NHWC bf16 (NB*HW, 384), ch 0..323 valid.
// grid 6144 blocks x 384 threads: lanes = consecutive channels at one pixel.
// ---------------------------------------------------------------------------
__global__ __launch_bounds__(384) void lookup_k(
    const ushort_t* __restrict__ l0, const ushort_t* __restrict__ l1,
    const ushort_t* __restrict__ l2, const ushort_t* __restrict__ l3,
    const float* __restrict__ flow, ushort_t* __restrict__ out) {
  const int c = threadIdx.x;
  const int p = blockIdx.x;
  if (c >= 324) return;
  const int nb = p / HW;
  const int rem = p - nb * HW;
  const int yy = rem >> 6, xx = rem & 63;
  const float fx = flow[((size_t)(nb * 2 + 0)) * HW + rem];
  const float fy = flow[((size_t)(nb * 2 + 1)) * HW + rem];
  const int l = c / 81;
  const int k = c - l * 81;
  const float dx = (float)(k / 9) - 4.f;
  const float dy = (float)(k - (k / 9) * 9) - 4.f;
  const int hl = HH >> l, wl = WW >> l;
  const ushort_t* base = (l == 0) ? l0 : (l == 1) ? l1 : (l == 2) ? l2 : l3;
  const ushort_t* img = base + (size_t)p * (hl * wl);
  const float s = 1.f / (float)(1 << l);
  const float xl = ((float)xx + fx) * s + dx;
  const float yl = ((float)yy + fy) * s + dy;
  const float x0f = floorf(xl), y0f = floorf(yl);
  float acc = 0.f;
#pragma unroll
  for (int dy2 = 0; dy2 < 2; ++dy2) {
#pragma unroll
    for (int dx2 = 0; dx2 < 2; ++dx2) {
      const float xi = x0f + dx2, yi = y0f + dy2;
      if (xi >= 0.f && xi <= (float)(wl - 1) && yi >= 0.f && yi <= (float)(hl - 1)) {
        const float wv = (1.f - fabsf(xl - xi)) * (1.f - fabsf(yl - yi));
        acc += wv * bf2f(img[(int)yi * wl + (int)xi]);
      }
    }
  }
  out[(size_t)p * 384 + c] = f2bf(acc);
}

// ---------------------------------------------------------------------------
// MFMA implicit-GEMM conv.
// Activations NHWC bf16. Block = 4 waves: msub = wave&1 (16 pixels each),
// nsub = wave>>1 (64 out-ch each, 4x 16x16x32 MFMA per K-step).
// M-tile 32 pixels (half row), grid (96, CO_pad/128, NB2).
// MODE 0: single src xa (stride CIT_A, offset ci_base)
// MODE 1: split net(128ch)/X(256ch); MODE 2: split + net*r (r = zr ch 128+c)
// UPD: y = (1-z)*old + z*act(...); FOUT: planar f32 output.
// ---------------------------------------------------------------------------
template <int KH, int KW, int PH, int PW, int ACT, int MODE, bool UPD, bool FOUT>
__global__ __launch_bounds__(256) void conv_mfma_k(
    const ushort_t* __restrict__ xa, const ushort_t* __restrict__ xb,
    const ushort_t* __restrict__ zr, const ushort_t* __restrict__ old_,
    const ushort_t* __restrict__ PB, const float* __restrict__ bias,
    void* __restrict__ yv, int NCHUNK, int CIT_A, int ci_base,
    int co_base, int CO_TOT, int co_limit, float scale) {
  constexpr int COLS = 32 + 2 * PW;
  constexpr int KHKW = KH * KW;
  __shared__ ushort_t als[KH * COLS * CCP];
  const int tid = threadIdx.x;
  const int l = tid & 63;
  const int wave = tid >> 6;
  const int msub = wave & 1;
  const int nsub = wave >> 1;
  const int nb = blockIdx.z;
  const int p0 = blockIdx.x * 32;
  const int y0 = p0 >> 6;
  const int x0 = p0 & 63;
  const int nbase = blockIdx.y * 8 + nsub * 4;
  const int KST = NCHUNK * KHKW * 2;
  const int q = (l >> 4) & 3;
  const int m = l & 15;

  f32x4 acc0 = {0.f, 0.f, 0.f, 0.f}, acc1 = acc0, acc2 = acc0, acc3 = acc0;
  const ushort_t* pb0 = PB + ((size_t)(nbase + 0) * KST * 64 + l) * 8;
  const ushort_t* pb1 = PB + ((size_t)(nbase + 1) * KST * 64 + l) * 8;
  const ushort_t* pb2 = PB + ((size_t)(nbase + 2) * KST * 64 + l) * 8;
  const ushort_t* pb3 = PB + ((size_t)(nbase + 3) * KST * 64 + l) * 8;
  const int aoff_lane = (msub * 16 + m) * CCP + q * 8;

  for (int c64 = 0; c64 < NCHUNK; ++c64) {
    __syncthreads();
    // stage input tile: KH rows x COLS cols x 64 ch (bf16), zero-padded
    constexpr int TOTU = KH * COLS * 8;
    for (int u = tid; u < TOTU; u += 256) {
      const int cc8 = u & 7;
      const int colr = u >> 3;
      const int col = colr % COLS;
      const int row = colr / COLS;
      const int gy = y0 + row - PH;
      const int gx = x0 + col - PW;
      uint4 v = {0u, 0u, 0u, 0u};
      if ((unsigned)gy < 48u && (unsigned)gx < 64u) {
        const size_t pix = (size_t)nb * HW + gy * 64 + gx;
        const int gc = c64 * 64 + cc8 * 8;
        if (MODE == 0) {
          v = *(const uint4*)(xa + pix * CIT_A + ci_base + gc);
        } else if (gc < 128) {
          v = *(const uint4*)(xa + pix * 128 + gc);
          if (MODE == 2) {
            const uint4 r = *(const uint4*)(zr + pix * 256 + 128 + gc);
            v.x = mulbf2(v.x, r.x); v.y = mulbf2(v.y, r.y);
            v.z = mulbf2(v.z, r.z); v.w = mulbf2(v.w, r.w);
          }
        } else {
          v = *(const uint4*)(xb + pix * 256 + (gc - 128));
        }
      }
      *(uint4*)&als[(row * COLS + col) * CCP + cc8 * 8] = v;
    }
    __syncthreads();
    const int sbase = c64 * KHKW * 2;
#pragma unroll
    for (int kh = 0; kh < KH; ++kh) {
#pragma unroll
      for (int kw = 0; kw < KW; ++kw) {
#pragma unroll
        for (int half = 0; half < 2; ++half) {
          const int s = sbase + (kh * KW + kw) * 2 + half;
          const bfx8 a = *(const bfx8*)&als[kh * COLS * CCP + kw * CCP + half * 32 + aoff_lane];
          const bfx8 b0 = *(const bfx8*)(pb0 + (size_t)s * 512);
          const bfx8 b1 = *(const bfx8*)(pb1 + (size_t)s * 512);
          const bfx8 b2 = *(const bfx8*)(pb2 + (size_t)s * 512);
          const bfx8 b3 = *(const bfx8*)(pb3 + (size_t)s * 512);
          acc0 = __builtin_amdgcn_mfma_f32_16x16x32_bf16(a, b0, acc0, 0, 0, 0);
          acc1 = __builtin_amdgcn_mfma_f32_16x16x32_bf16(a, b1, acc1, 0, 0, 0);
          acc2 = __builtin_amdgcn_mfma_f32_16x16x32_bf16(a, b2, acc2, 0, 0, 0);
          acc3 = __builtin_amdgcn_mfma_f32_16x16x32_bf16(a, b3, acc3, 0, 0, 0);
        }
      }
    }
  }
  // epilogue: C/D layout col(n)=lane&15, row(m)=(lane>>4)*4+reg
  const f32x4 accs[4] = {acc0, acc1, acc2, acc3};
#pragma unroll
  for (int f = 0; f < 4; ++f) {
    const int co = (nbase + f) * 16 + m;
    const float b = bias[co];
#pragma unroll
    for (int reg = 0; reg < 4; ++reg) {
      const int row = q * 4 + reg;
      const int p = p0 + msub * 16 + row;
      float v = accs[f][reg] + b;
      if (ACT == 1) v = fmaxf(v, 0.f);
      if (ACT == 2) v = 1.f / (1.f + __expf(-v));
      if (ACT == 3) v = tanhf(v);
      v *= scale;
      const size_t pix = (size_t)nb * HW + p;
      if (UPD) {
        const float z = bf2f(zr[pix * 256 + co]);
        const float old = bf2f(old_[pix * 128 + co]);
        v = (1.f - z) * old + z * v;
      }
      if (co_base + co < co_limit) {
        if (FOUT)
          ((float*)yv)[((size_t)nb * CO_TOT + co_base + co) * HW + p] = v;
        else
          ((ushort_t*)yv)[pix * CO_TOT + co_base + co] = f2bf(v);
      }
    }
  }
}

// ---------------------------------------------------------------------------
// mf1: 7x7 conv, 2ch -> 128ch, flow f32 planar -> FLO NHWC bf16 (relu)
// grid (48, NB2), block 256: lanes = 64 pixels, (tid>>6)*32 = co group
// ---------------------------------------------------------------------------
__global__ __launch_bounds__(256) void mf1_k(const float* __restrict__ flow,
                                             const float* __restrict__ w,
                                             const float* __restrict__ bias,
                                             ushort_t* __restrict__ flo) {
  __shared__ float wl[12544];
  const int tid = threadIdx.x;
  for (int e = tid; e < 12544; e += 256) {
    const int co = e & 127;
    const int rest = e >> 7;
    const int ci = rest / 49;
    const int t = rest - ci * 49;
    wl[e] = w[((size_t)co * 2 + ci) * 49 + t];
  }
  __syncthreads();
  const int nb = blockIdx.y;
  const int p = blockIdx.x * 64 + (tid & 63);
  const int cg = (tid >> 6) * 32;
  const int y = p >> 6, x = p & 63;
  float acc[32];
#pragma unroll
  for (int c = 0; c < 32; ++c) acc[c] = bias[cg + c];
  for (int ci = 0; ci < 2; ++ci) {
    const float* fp = flow + (size_t)(nb * 2 + ci) * HW;
    for (int t = 0; t < 49; ++t) {
      const int gy = y + t / 7 - 3;
      const int gx = x + t % 7 - 3;
      float f = 0.f;
      if ((unsigned)gy < 48u && (unsigned)gx < 64u) f = fp[gy * 64 + gx];
      const float* wp = &wl[(ci * 49 + t) * 128 + cg];
#pragma unroll
      for (int c = 0; c < 32; ++c) acc[c] = fmaf(f, wp[c], acc[c]);
    }
  }
  ushort_t* op = flo + ((size_t)nb * HW + p) * 128 + cg;
#pragma unroll
  for (int c = 0; c < 32; ++c) op[c] = f2bf(fmaxf(acc[c], 0.f));
}

// ---------------------------------------------------------------------------
// small elementwise kernels
// ---------------------------------------------------------------------------
__global__ __launch_bounds__(256) void init_k(const float* __restrict__ cnet,
                                              ushort_t* __restrict__ net,
                                              ushort_t* __restrict__ X) {
  int idx = blockIdx.x * 256 + threadIdx.x;
  if (idx >= NB2 * 128 * HW) return;
  int nb = idx / (128 * HW);
  int r = idx - nb * 128 * HW;
  int c = r / HW;
  int p = r - c * HW;
  float vn = cnet[((size_t)(nb * 256 + c)) * HW + p];
  float vi = cnet[((size_t)(nb * 256 + 128 + c)) * HW + p];
  net[((size_t)nb * HW + p) * 128 + c] = f2bf(tanhf(vn));
  X[((size_t)nb * HW + p) * 256 + c] = f2bf(fmaxf(vi, 0.f));
}

__global__ __launch_bounds__(256) void flow2x_k(const float* __restrict__ flow,
                                                ushort_t* __restrict__ X) {
  int i = blockIdx.x * 256 + threadIdx.x;
  if (i >= NB2 * 2 * HW) return;
  int nb = i / (2 * HW);
  int r = i - nb * 2 * HW;
  int ch = r / HW;
  int p = r - ch * HW;
  X[((size_t)nb * HW + p) * 256 + 254 + ch] = f2bf(flow[i]);
}

__global__ __launch_bounds__(256) void flow_update_k(float* __restrict__ flow,
                                                     float* __restrict__ eflow,
                                                     const float* __restrict__ df,
                                                     const float* __restrict__ edf) {
  int i = blockIdx.x * 256 + threadIdx.x;
  if (i < NB2 * 2 * HW) {
    float e = edf[i];
    flow[i] += df[i] + e;
    eflow[i] += e;
  }
}

// convex upsample; mask now NHWC bf16 (576 wide, 0.25 pre-scaled)
__global__ __launch_bounds__(256) void upsample_k(const float* __restrict__ flow,
                                                  const ushort_t* __restrict__ mask,
                                                  float* __restrict__ out) {
  const int j = threadIdx.x & 7;
  const int xh = threadIdx.x >> 3;
  const int x = blockIdx.x * 32 + xh;
  const int i = blockIdx.y;
  const int nz = blockIdx.z;
  const int nb = nz / 48, yy = nz - nb * 48;
  const int rem = yy * 64 + x;
  const ushort_t* mp = mask + ((size_t)nb * HW + rem) * 576;
  float m[9];
  float mx = -1e30f;
#pragma unroll
  for (int k = 0; k < 9; ++k) {
    m[k] = bf2f(mp[k * 64 + i * 8 + j]);
    mx = fmaxf(mx, m[k]);
  }
  float sum = 0.f;
#pragma unroll
  for (int k = 0; k < 9; ++k) {
    m[k] = __expf(m[k] - mx);
    sum += m[k];
  }
  const float inv = 8.f / sum;
#pragma unroll
  for (int ch = 0; ch < 2; ++ch) {
    float acc = 0.f;
#pragma unroll
    for (int k = 0; k < 9; ++k) {
      const int gy = yy + k / 3 - 1;
      const int gx = x + (k - (k / 3) * 3) - 1;
      float f = 0.f;
      if ((unsigned)gy < 48u && (unsigned)gx < 64u)
        f = flow[((size_t)(nb * 2 + ch)) * HW + gy * 64 + gx];
      acc = fmaf(m[k], f, acc);
    }
    out[(((size_t)(nb * 2 + ch)) * 384 + (yy * 8 + i)) * 512 + x * 8 + j] = acc * inv;
  }
}

// ---------------------------------------------------------------------------
// host orchestration
// ---------------------------------------------------------------------------
extern "C" void kernel_launch(void* const* d_in, const int* in_sizes, int n_in,
                              void* d_out, int out_size, void* d_ws, size_t ws_size,
                              hipStream_t stream) {
  (void)in_sizes; (void)n_in; (void)out_size;

  size_t off = 0;
  char* base = (char*)d_ws;
  auto take = [&](size_t nbytes) -> void* {
    void* p = base + off;
    off += (nbytes + 255) & ~(size_t)255;
    return p;
  };
  ushort_t* pyrA[4];
  ushort_t* pyrB[4];
  const int lsz[4] = {3072, 768, 192, 48};
  for (int l = 0; l < 4; ++l) pyrA[l] = (ushort_t*)take((size_t)NP * lsz[l] * 2);
  for (int l = 0; l < 4; ++l) pyrB[l] = (ushort_t*)take((size_t)NP * lsz[l] * 2);
  float* FM[6];
  for (int s = 0; s < 6; ++s) FM[s] = (float*)take((size_t)NB2 * 256 * HW * 4);
  // NHWC bf16 activation buffers
  ushort_t* CORR = (ushort_t*)take((size_t)NP * 384 * 2);
  ushort_t* ECORR = (ushort_t*)take((size_t)NP * 384 * 2);
  ushort_t* NET = (ushort_t*)take((size_t)NP * 128 * 2);
  ushort_t* ENET = (ushort_t*)take((size_t)NP * 128 * 2);
  ushort_t* NETB = (ushort_t*)take((size_t)NP * 128 * 2);
  ushort_t* X1 = (ushort_t*)take((size_t)NP * 256 * 2);
  ushort_t* X2 = (ushort_t*)take((size_t)NP * 256 * 2);
  ushort_t* ACT1 = (ushort_t*)take((size_t)NP * 256 * 2);
  ushort_t* CFB = (ushort_t*)take((size_t)NP * 256 * 2);
  ushort_t* FLO = (ushort_t*)take((size_t)NP * 128 * 2);
  ushort_t* ZRB = (ushort_t*)take((size_t)NP * 256 * 2);
  ushort_t* A512 = (ushort_t*)take((size_t)NP * 512 * 2);
  ushort_t* MASKB = (ushort_t*)take((size_t)NP * 576 * 2);
  float* FLOW = (float*)take((size_t)NB2 * 2 * HW * 4);
  float* EFLOW = (float*)take((size_t)NB2 * 2 * HW * 4);
  float* DF = (float*)take((size_t)NB2 * 2 * HW * 4);
  float* EDF = (float*)take((size_t)NB2 * 2 * HW * 4);

  static const int WSZ[15] = {82944, 442368, 12544, 73728, 290304,
                              245760, 245760, 245760, 245760, 245760, 245760,
                              294912, 4608, 294912, 147456};
  static const int BSZ[15] = {256, 192, 128, 64, 126, 128, 128, 128,
                              128, 128, 128, 256, 2, 256, 576};
  float* Wf[15];
  float* Bf[15];
  for (int s = 0; s < 5; ++s) Wf[s] = (float*)take((size_t)WSZ[s] * 4);
  Wf[5] = (float*)take((size_t)2 * 245760 * 4); Wf[6] = Wf[5] + 245760;
  Wf[7] = (float*)take((size_t)245760 * 4);
  Wf[8] = (float*)take((size_t)2 * 245760 * 4); Wf[9] = Wf[8] + 245760;
  Wf[10] = (float*)take((size_t)245760 * 4);
  Wf[11] = (float*)take((size_t)2 * 294912 * 4); Wf[13] = Wf[11] + 294912;
  Wf[12] = (float*)take((size_t)4608 * 4);
  Wf[14] = (float*)take((size_t)147456 * 4);
  for (int s = 0; s < 5; ++s) Bf[s] = (float*)take((size_t)BSZ[s] * 4);
  Bf[5] = (float*)take((size_t)2 * 128 * 4); Bf[6] = Bf[5] + 128;
  Bf[7] = (float*)take((size_t)128 * 4);
  Bf[8] = (float*)take((size_t)2 * 128 * 4); Bf[9] = Bf[8] + 128;
  Bf[10] = (float*)take((size_t)128 * 4);
  Bf[11] = (float*)take((size_t)2 * 256 * 4); Bf[13] = Bf[11] + 256;
  Bf[12] = (float*)take((size_t)2 * 4);
  Bf[14] = (float*)take((size_t)576 * 4);
  // packed B-fragment weights (bf16)
  // sizes in ushorts: (CO_pad/16) * NCHUNK*KHKW*2 * 512
  ushort_t* PBmc1 = (ushort_t*)take((size_t)16 * 12 * 512 * 2);
  ushort_t* PBmc2 = (ushort_t*)take((size_t)16 * 72 * 512 * 2);
  ushort_t* PBmf2 = (ushort_t*)take((size_t)8 * 36 * 512 * 2);
  ushort_t* PBmo  = (ushort_t*)take((size_t)8 * 72 * 512 * 2);
  ushort_t* PBgzr1 = (ushort_t*)take((size_t)16 * 60 * 512 * 2);
  ushort_t* PBgq1 = (ushort_t*)take((size_t)8 * 60 * 512 * 2);
  ushort_t* PBgzr2 = (ushort_t*)take((size_t)16 * 60 * 512 * 2);
  ushort_t* PBgq2 = (ushort_t*)take((size_t)8 * 60 * 512 * 2);
  ushort_t* PBfh = (ushort_t*)take((size_t)32 * 36 * 512 * 2);
  ushort_t* PBmk2 = (ushort_t*)take((size_t)40 * 8 * 512 * 2);
  ushort_t* PBfh2 = (ushort_t*)take((size_t)8 * 72 * 512 * 2);
  int* FLAG = (int*)take(256);

  if (off > ws_size) return;

  detect_k<<<1, 256, 0, stream>>>((const ushort_t*)d_in[0], FLAG);
  CvtArgs ca;
  for (int s = 0; s < 6; ++s) {
    ca.src[s] = d_in[s];
    ca.dst[s] = FM[s];
    ca.n[s] = NB2 * 256 * HW;
  }
  for (int s = 0; s < 15; ++s) {
    ca.src[6 + s] = d_in[6 + 2 * s];
    ca.dst[6 + s] = Wf[s];
    ca.n[6 + s] = WSZ[s];
    ca.src[21 + s] = d_in[7 + 2 * s];
    ca.dst[21 + s] = Bf[s];
    ca.n[21 + s] = BSZ[s];
  }
  cvt_all_k<<<1024, 256, 0, stream>>>(ca, FLAG);

  // pack weights into B-fragment order
  auto pack = [&](const float* src, ushort_t* dst, int CO, int NB16, int CI, int KHKW, int NCH) {
    int total = NB16 * NCH * KHKW * 2 * 512;
    pack_k<<<(total + 255) / 256, 256, 0, stream>>>(src, dst, CO, CI, KHKW, NCH, total);
  };
  pack(Wf[0], PBmc1, 256, 16, 324, 1, 6);
  pack(Wf[1], PBmc2, 192, 16, 256, 9, 4);
  pack(Wf[3], PBmf2, 64, 8, 128, 9, 2);
  pack(Wf[4], PBmo, 126, 8, 256, 9, 4);
  pack(Wf[5], PBgzr1, 256, 16, 384, 5, 6);
  pack(Wf[7], PBgq1, 128, 8, 384, 5, 6);
  pack(Wf[8], PBgzr2, 256, 16, 384, 5, 6);
  pack(Wf[10], PBgq2, 128, 8, 384, 5, 6);
  pack(Wf[11], PBfh, 512, 32, 128, 9, 2);
  pack(Wf[14], PBmk2, 576, 40, 256, 1, 4);
  pack(Wf[12], PBfh2, 2, 8, 256, 9, 4);

  corr_gemm_k<<<dim3(48, 48, NB2), 256, 0, stream>>>(FM[0], FM[1], pyrA[0]);
  corr_gemm_k<<<dim3(48, 48, NB2), 256, 0, stream>>>(FM[2], FM[3], pyrB[0]);
  {
    const int wsv[4] = {64, 32, 16, 8};
    const int hsv[4] = {48, 24, 12, 6};
    for (int l = 0; l < 3; ++l) {
      int ho = hsv[l + 1], wo = wsv[l + 1];
      int total = NP * ho * wo;
      avgpool_k<<<(total + 255) / 256, 256, 0, stream>>>(pyrA[l], pyrA[l + 1], wsv[l], ho, wo, total);
      avgpool_k<<<(total + 255) / 256, 256, 0, stream>>>(pyrB[l], pyrB[l + 1], wsv[l], ho, wo, total);
    }
  }
  init_k<<<(NB2 * 128 * HW + 255) / 256, 256, 0, stream>>>(FM[4], NET, X1);
  init_k<<<(NB2 * 128 * HW + 255) / 256, 256, 0, stream>>>(FM[5], ENET, X2);
  hipMemsetAsync(FLOW, 0, (size_t)NB2 * 2 * HW * 4, stream);
  hipMemsetAsync(EFLOW, 0, (size_t)NB2 * 2 * HW * 4, stream);

  float* outp = (float*)d_out;
  const ushort_t* NUL = nullptr;

  auto ub = [&](ushort_t* NETp, ushort_t* Xp, const ushort_t* CORRp,
                const float* FLOWp, float* DFp, bool domask) {
    // motion encoder
    conv_mfma_k<1, 1, 0, 0, 1, 0, false, false><<<dim3(96, 2, NB2), 256, 0, stream>>>(
        CORRp, NUL, NUL, NUL, PBmc1, Bf[0], ACT1, 6, 384, 0, 0, 256, 256, 1.f);
    conv_mfma_k<3, 3, 1, 1, 1, 0, false, false><<<dim3(96, 2, NB2), 256, 0, stream>>>(
        ACT1, NUL, NUL, NUL, PBmc2, Bf[1], CFB, 4, 256, 0, 0, 256, 256, 1.f);
    mf1_k<<<dim3(48, NB2), 256, 0, stream>>>(FLOWp, Wf[2], Bf[2], FLO);
    conv_mfma_k<3, 3, 1, 1, 1, 0, false, false><<<dim3(96, 1, NB2), 256, 0, stream>>>(
        FLO, NUL, NUL, NUL, PBmf2, Bf[3], CFB, 2, 128, 0, 192, 256, 256, 1.f);
    conv_mfma_k<3, 3, 1, 1, 1, 0, false, false><<<dim3(96, 1, NB2), 256, 0, stream>>>(
        CFB, NUL, NUL, NUL, PBmo, Bf[4], Xp, 4, 256, 0, 128, 256, 256, 1.f);
    flow2x_k<<<48, 256, 0, stream>>>(FLOWp, Xp);
    // GRU horizontal (1x5)
    conv_mfma_k<1, 5, 0, 2, 2, 1, false, false><<<dim3(96, 2, NB2), 256, 0, stream>>>(
        NETp, Xp, NUL, NUL, PBgzr1, Bf[5], ZRB, 6, 0, 0, 0, 256, 256, 1.f);
    conv_mfma_k<1, 5, 0, 2, 3, 2, true, false><<<dim3(96, 1, NB2), 256, 0, stream>>>(
        NETp, Xp, ZRB, NETp, PBgq1, Bf[7], NETB, 6, 0, 0, 0, 128, 128, 1.f);
    // GRU vertical (5x1)
    conv_mfma_k<5, 1, 2, 0, 2, 1, false, false><<<dim3(96, 2, NB2), 256, 0, stream>>>(
        NETB, Xp, NUL, NUL, PBgzr2, Bf[8], ZRB, 6, 0, 0, 0, 256, 256, 1.f);
    conv_mfma_k<5, 1, 2, 0, 3, 2, true, false><<<dim3(96, 1, NB2), 256, 0, stream>>>(
        NETB, Xp, ZRB, NETB, PBgq2, Bf[10], NETp, 6, 0, 0, 0, 128, 128, 1.f);
    // heads
    conv_mfma_k<3, 3, 1, 1, 1, 0, false, false><<<dim3(96, domask ? 4 : 2, NB2), 256, 0, stream>>>(
        NETp, NUL, NUL, NUL, PBfh, Bf[11], A512, 2, 128, 0, 0, 512, 512, 1.f);
    conv_mfma_k<3, 3, 1, 1, 0, 0, false, true><<<dim3(96, 1, NB2), 256, 0, stream>>>(
        A512, NUL, NUL, NUL, PBfh2, Bf[12], DFp, 4, 512, 0, 0, 2, 2, 1.f);
    if (domask) {
      conv_mfma_k<1, 1, 0, 0, 0, 0, false, false><<<dim3(96, 5, NB2), 256, 0, stream>>>(
          A512, NUL, NUL, NUL, PBmk2, Bf[14], MASKB, 4, 512, 256, 0, 576, 576, 0.25f);
    }
  };

  for (int it = 0; it < ITERS; ++it) {
    lookup_k<<<6144, 384, 0, stream>>>(pyrA[0], pyrA[1], pyrA[2], pyrA[3], FLOW, CORR);
    lookup_k<<<6144, 384, 0, stream>>>(pyrB[0], pyrB[1], pyrB[2], pyrB[3], EFLOW, ECORR);
    ub(NET, X1, CORR, FLOW, DF, true);
    ub(ENET, X2, ECORR, EFLOW, EDF, false);
    flow_update_k<<<48, 256, 0, stream>>>(FLOW, EFLOW, DF, EDF);
    upsample_k<<<dim3(2, 8, 96), 256, 0, stream>>>(FLOW, MASKB,
                                                   outp + (size_t)it * (NB2 * 2 * 384 * 512));
  }
}

// Round 6
// 4689.696 us; speedup vs baseline: 21.4114x; 1.6905x over previous
//
#include <hip/hip_runtime.h>
#include <stdint.h>

typedef unsigned short ushort_t;
using bfx8 = __attribute__((ext_vector_type(8))) short;
using f32x4 = __attribute__((ext_vector_type(4))) float;

#define DEVINL static __device__ __forceinline__

DEVINL float bits2f(unsigned int b) { union { unsigned int i; float f; } v; v.i = b; return v.f; }
DEVINL float bf2f(ushort_t u) { return bits2f(((unsigned int)u) << 16); }
DEVINL ushort_t f2bf(float x) {
  union { float f; unsigned int i; } v; v.f = x;
  return (ushort_t)((v.i + 0x7FFFu + ((v.i >> 16) & 1u)) >> 16);
}
DEVINL unsigned int mulbf2(unsigned int a, unsigned int r) {
  float a0 = bits2f(a << 16), a1 = bits2f(a & 0xFFFF0000u);
  float r0 = bits2f(r << 16), r1 = bits2f(r & 0xFFFF0000u);
  return (unsigned int)f2bf(a0 * r0) | ((unsigned int)f2bf(a1 * r1) << 16);
}

constexpr int NB2 = 2;
constexpr int HH = 48, WW = 64, HW = 3072;
constexpr int NP = NB2 * HW;
constexpr int ITERS = 12;
constexpr int CCP = 72;  // 64 channels + 8 pad

// ---------------------------------------------------------------------------
// dtype detect + weight conversion
// ---------------------------------------------------------------------------
__global__ __launch_bounds__(256) void detect_k(const ushort_t* __restrict__ src,
                                                int* __restrict__ flag) {
  const int t = threadIdx.x;
  int bad = 0;
  for (int i = t; i < 4096; i += 256) {
    const float v = bf2f(src[i]);
    if (!(fabsf(v) < 1e30f)) bad = 1;
  }
  __shared__ int s;
  if (t == 0) s = 0;
  __syncthreads();
  if (bad) atomicOr(&s, 1);
  __syncthreads();
  if (t == 0) *flag = s;
}

struct CvtArgs {
  const void* src[30];
  float* dst[30];
  int n[30];
};
__global__ __launch_bounds__(256) void cvt_all_k(CvtArgs a, const int* __restrict__ flag) {
  const bool isf32 = (*flag != 0);
  const int stride = gridDim.x * 256;
  const int t0 = blockIdx.x * 256 + threadIdx.x;
  for (int s = 0; s < 30; ++s) {
    float* dst = a.dst[s];
    const int n = a.n[s];
    if (isf32) {
      const float* src = (const float*)a.src[s];
      for (int i = t0; i < n; i += stride) dst[i] = src[i];
    } else {
      const ushort_t* src = (const ushort_t*)a.src[s];
      for (int i = t0; i < n; i += stride) dst[i] = bf2f(src[i]);
    }
  }
}

// transpose fmap (2,256,48,64) -> NHWC bf16 (NB2*HW, 256); grid y = tensor
__global__ __launch_bounds__(256) void trans_k(const void* s0, const void* s1,
                                               const void* s2, const void* s3,
                                               ushort_t* d0, ushort_t* d1,
                                               ushort_t* d2, ushort_t* d3,
                                               const int* __restrict__ flag) {
  const bool isf32 = (*flag != 0);
  int idx = blockIdx.x * 256 + threadIdx.x;
  if (idx >= NP * 256) return;
  const int t = blockIdx.y;
  const int c = idx & 255;
  const int p = idx >> 8;
  const int nb = (p >= HW) ? 1 : 0;
  const int pp = p - nb * HW;
  const void* s = (t == 0) ? s0 : (t == 1) ? s1 : (t == 2) ? s2 : s3;
  ushort_t* d = (t == 0) ? d0 : (t == 1) ? d1 : (t == 2) ? d2 : d3;
  const size_t si = ((size_t)(nb * 256 + c)) * HW + pp;
  d[idx] = isf32 ? f2bf(((const float*)s)[si]) : ((const ushort_t*)s)[si];
}

// init hidden/context for both branches; grid y = branch
__global__ __launch_bounds__(256) void init2_k(const void* cnet, const void* enet,
                                               ushort_t* net0, ushort_t* net1,
                                               ushort_t* X0, ushort_t* X1v,
                                               const int* __restrict__ flag) {
  const bool isf32 = (*flag != 0);
  int idx = blockIdx.x * 256 + threadIdx.x;
  if (idx >= NB2 * 128 * HW) return;
  const int br = blockIdx.y;
  const void* s = br ? enet : cnet;
  ushort_t* N = br ? net1 : net0;
  ushort_t* X = br ? X1v : X0;
  int nb = idx / (128 * HW);
  int r = idx - nb * 128 * HW;
  int c = r / HW;
  int p = r - c * HW;
  const size_t i0 = ((size_t)(nb * 256 + c)) * HW + p;
  const size_t i1 = ((size_t)(nb * 256 + 128 + c)) * HW + p;
  float vn = isf32 ? ((const float*)s)[i0] : bf2f(((const ushort_t*)s)[i0]);
  float vi = isf32 ? ((const float*)s)[i1] : bf2f(((const ushort_t*)s)[i1]);
  N[((size_t)nb * HW + p) * 128 + c] = f2bf(tanhf(vn));
  X[((size_t)nb * HW + p) * 256 + c] = f2bf(fmaxf(vi, 0.f));
}

// ---------------------------------------------------------------------------
// weight pack: f32 (CO, CI, KH, KW) -> B-fragment order bf16
// ---------------------------------------------------------------------------
__global__ __launch_bounds__(256) void pack_k(const float* __restrict__ src,
                                              ushort_t* __restrict__ dst,
                                              int CO, int CI_real, int KHKW,
                                              int NCHUNK, int total) {
  int idx = blockIdx.x * 256 + threadIdx.x;
  if (idx >= total) return;
  const int KST = NCHUNK * KHKW * 2;
  const int j = idx & 7;
  const int l = (idx >> 3) & 63;
  const int s = (idx >> 9) % KST;
  const int b = idx / (512 * KST);
  const int chunk = s / (KHKW * 2);
  const int r = s - chunk * KHKW * 2;
  const int t = r >> 1;
  const int half = r & 1;
  const int ci = chunk * 64 + half * 32 + ((l >> 4) & 3) * 8 + j;
  const int n = b * 16 + (l & 15);
  float v = 0.f;
  if (n < CO && ci < CI_real) v = src[((size_t)n * CI_real + ci) * KHKW + t];
  dst[idx] = f2bf(v);
}

// ---------------------------------------------------------------------------
// correlation GEMM, bf16 MFMA. grid (96, 24, 4): z = pyr*2 + nb.
// Block M32 x N128; 4 waves: msub = wave&1 (16 pix), nsub = wave>>1 (64 N-pix)
// ---------------------------------------------------------------------------
struct CorrPtrs { const ushort_t* f[4]; ushort_t* out[2]; };
__global__ __launch_bounds__(256) void corr_mfma_k(CorrPtrs C) {
  const int z = blockIdx.z;
  const int pyr = z >> 1, nb = z & 1;
  const ushort_t* f1 = C.f[pyr * 2] + (size_t)nb * HW * 256;
  const ushort_t* f2 = C.f[pyr * 2 + 1] + (size_t)nb * HW * 256;
  ushort_t* out = C.out[pyr] + (size_t)nb * HW * HW;
  const int tid = threadIdx.x;
  const int l = tid & 63;
  const int wave = tid >> 6;
  const int msub = wave & 1, nsub = wave >> 1;
  const int m0 = blockIdx.x * 32, n0 = blockIdx.y * 128;
  const int q = (l >> 4) & 3, m = l & 15;
  __shared__ ushort_t als[32 * CCP];
  __shared__ ushort_t bls[128 * CCP];
  f32x4 acc0 = {0.f, 0.f, 0.f, 0.f}, acc1 = acc0, acc2 = acc0, acc3 = acc0;
  for (int c64 = 0; c64 < 4; ++c64) {
    __syncthreads();
    {
      const int cc8 = tid & 7, pixel = tid >> 3;
      *(uint4*)&als[pixel * CCP + cc8 * 8] =
          *(const uint4*)(f1 + ((size_t)(m0 + pixel)) * 256 + c64 * 64 + cc8 * 8);
    }
#pragma unroll
    for (int r = 0; r < 4; ++r) {
      const int u = tid + r * 256;
      const int cc8 = u & 7, pixel = u >> 3;
      *(uint4*)&bls[pixel * CCP + cc8 * 8] =
          *(const uint4*)(f2 + ((size_t)(n0 + pixel)) * 256 + c64 * 64 + cc8 * 8);
    }
    __syncthreads();
#pragma unroll
    for (int half = 0; half < 2; ++half) {
      const bfx8 a = *(const bfx8*)&als[(msub * 16 + m) * CCP + half * 32 + q * 8];
      const bfx8 b0 = *(const bfx8*)&bls[(nsub * 64 + 0 + m) * CCP + half * 32 + q * 8];
      const bfx8 b1 = *(const bfx8*)&bls[(nsub * 64 + 16 + m) * CCP + half * 32 + q * 8];
      const bfx8 b2 = *(const bfx8*)&bls[(nsub * 64 + 32 + m) * CCP + half * 32 + q * 8];
      const bfx8 b3 = *(const bfx8*)&bls[(nsub * 64 + 48 + m) * CCP + half * 32 + q * 8];
      acc0 = __builtin_amdgcn_mfma_f32_16x16x32_bf16(a, b0, acc0, 0, 0, 0);
      acc1 = __builtin_amdgcn_mfma_f32_16x16x32_bf16(a, b1, acc1, 0, 0, 0);
      acc2 = __builtin_amdgcn_mfma_f32_16x16x32_bf16(a, b2, acc2, 0, 0, 0);
      acc3 = __builtin_amdgcn_mfma_f32_16x16x32_bf16(a, b3, acc3, 0, 0, 0);
    }
  }
  const f32x4 accs[4] = {acc0, acc1, acc2, acc3};
#pragma unroll
  for (int f = 0; f < 4; ++f) {
#pragma unroll
    for (int reg = 0; reg < 4; ++reg) {
      const int mi = m0 + msub * 16 + q * 4 + reg;
      const int nj = n0 + nsub * 64 + f * 16 + m;
      out[(size_t)mi * HW + nj] = f2bf(accs[f][reg] * 0.0625f);
    }
  }
}

// 2x2 avg-pool, both pyramids per launch (grid y)
__global__ __launch_bounds__(256) void avgpool_k(const ushort_t* __restrict__ inA,
                                                 const ushort_t* __restrict__ inB,
                                                 ushort_t* __restrict__ outA,
                                                 ushort_t* __restrict__ outB,
                                                 int wi, int ho, int wo, int total) {
  int idx = blockIdx.x * 256 + threadIdx.x;
  if (idx >= total) return;
  const ushort_t* in = blockIdx.y ? inB : inA;
  ushort_t* out = blockIdx.y ? outB : outA;
  int pw = ho * wo;
  int p = idx / pw;
  int r = idx - p * pw;
  int y = r / wo;
  int x = r - y * wo;
  const ushort_t* src = in + (size_t)p * (4 * pw) + (2 * y) * wi + 2 * x;
  float v = (bf2f(src[0]) + bf2f(src[1]) + bf2f(src[wi]) + bf2f(src[wi + 1])) * 0.25f;
  out[idx] = f2bf(v);
}

// ---------------------------------------------------------------------------
// correlation lookup, both branches per launch (grid y = branch)
// ---------------------------------------------------------------------------
struct LkPtrs {
  const ushort_t* a0; const ushort_t* a1; const ushort_t* a2; const ushort_t* a3;
  const ushort_t* b0; const ushort_t* b1; const ushort_t* b2; const ushort_t* b3;
  const float* flow[2];
  ushort_t* out[2];
};
__global__ __launch_bounds__(384) void lookup_k(LkPtrs P) {
  const int c = threadIdx.x;
  const int p = blockIdx.x;
  const int br = blockIdx.y;
  if (c >= 324) return;
  const int nb = p / HW;
  const int rem = p - nb * HW;
  const int yy = rem >> 6, xx = rem & 63;
  const float* flow = P.flow[br];
  const float fx = flow[((size_t)(nb * 2 + 0)) * HW + rem];
  const float fy = flow[((size_t)(nb * 2 + 1)) * HW + rem];
  const int l = c / 81;
  const int k = c - l * 81;
  const float dx = (float)(k / 9) - 4.f;
  const float dy = (float)(k - (k / 9) * 9) - 4.f;
  const int hl = HH >> l, wl = WW >> l;
  const ushort_t* base =
      br ? ((l == 0) ? P.b0 : (l == 1) ? P.b1 : (l == 2) ? P.b2 : P.b3)
         : ((l == 0) ? P.a0 : (l == 1) ? P.a1 : (l == 2) ? P.a2 : P.a3);
  const ushort_t* img = base + (size_t)p * (hl * wl);
  const float s = 1.f / (float)(1 << l);
  const float xl = ((float)xx + fx) * s + dx;
  const float yl = ((float)yy + fy) * s + dy;
  const float x0f = floorf(xl), y0f = floorf(yl);
  float acc = 0.f;
#pragma unroll
  for (int dy2 = 0; dy2 < 2; ++dy2) {
#pragma unroll
    for (int dx2 = 0; dx2 < 2; ++dx2) {
      const float xi = x0f + dx2, yi = y0f + dy2;
      if (xi >= 0.f && xi <= (float)(wl - 1) && yi >= 0.f && yi <= (float)(hl - 1)) {
        const float wv = (1.f - fabsf(xl - xi)) * (1.f - fabsf(yl - yi));
        acc += wv * bf2f(img[(int)yi * wl + (int)xi]);
      }
    }
  }
  P.out[br][(size_t)p * 384 + c] = f2bf(acc);
}

// ---------------------------------------------------------------------------
// MFMA implicit-GEMM conv, branch-merged. grid (96, COpad/128, nbr*2).
// nbr==2: z = br*2+nb; nbr==1: br=0, nb=z. Branch1 skips blockIdx.y >= ylim1.
// ---------------------------------------------------------------------------
struct BrPtrs {
  const ushort_t* xa[2]; const ushort_t* xb[2];
  const ushort_t* zr[2]; const ushort_t* old_[2];
  void* y[2];
};
template <int KH, int KW, int PH, int PW, int ACT, int MODE, bool UPD, bool FOUT>
__global__ __launch_bounds__(256) void conv_mfma_k(
    BrPtrs P, const ushort_t* __restrict__ PB, const float* __restrict__ bias,
    int NCHUNK, int CIT_A, int ci_base, int co_base, int CO_TOT, int co_limit,
    float scale, int nbr, int ylim1) {
  constexpr int COLS = 32 + 2 * PW;
  constexpr int KHKW = KH * KW;
  __shared__ ushort_t als[KH * COLS * CCP];
  const int z = blockIdx.z;
  const int br = (nbr == 2) ? (z >> 1) : 0;
  const int nb = (nbr == 2) ? (z & 1) : z;
  if (br == 1 && (int)blockIdx.y >= ylim1) return;
  const ushort_t* xa = P.xa[br];
  const ushort_t* xb = P.xb[br];
  const ushort_t* zr = P.zr[br];
  const ushort_t* old_ = P.old_[br];
  void* yv = P.y[br];

  const int tid = threadIdx.x;
  const int l = tid & 63;
  const int wave = tid >> 6;
  const int msub = wave & 1;
  const int nsub = wave >> 1;
  const int p0 = blockIdx.x * 32;
  const int y0 = p0 >> 6;
  const int x0 = p0 & 63;
  const int nbase = blockIdx.y * 8 + nsub * 4;
  const int KST = NCHUNK * KHKW * 2;
  const int q = (l >> 4) & 3;
  const int m = l & 15;

  f32x4 acc0 = {0.f, 0.f, 0.f, 0.f}, acc1 = acc0, acc2 = acc0, acc3 = acc0;
  const ushort_t* pb0 = PB + ((size_t)(nbase + 0) * KST * 64 + l) * 8;
  const ushort_t* pb1 = PB + ((size_t)(nbase + 1) * KST * 64 + l) * 8;
  const ushort_t* pb2 = PB + ((size_t)(nbase + 2) * KST * 64 + l) * 8;
  const ushort_t* pb3 = PB + ((size_t)(nbase + 3) * KST * 64 + l) * 8;
  const int aoff_lane = (msub * 16 + m) * CCP + q * 8;

  for (int c64 = 0; c64 < NCHUNK; ++c64) {
    __syncthreads();
    constexpr int TOTU = KH * COLS * 8;
    for (int u = tid; u < TOTU; u += 256) {
      const int cc8 = u & 7;
      const int colr = u >> 3;
      const int col = colr % COLS;
      const int row = colr / COLS;
      const int gy = y0 + row - PH;
      const int gx = x0 + col - PW;
      uint4 v = {0u, 0u, 0u, 0u};
      if ((unsigned)gy < 48u && (unsigned)gx < 64u) {
        const size_t pix = (size_t)nb * HW + gy * 64 + gx;
        const int gc = c64 * 64 + cc8 * 8;
        if (MODE == 0) {
          v = *(const uint4*)(xa + pix * CIT_A + ci_base + gc);
        } else if (gc < 128) {
          v = *(const uint4*)(xa + pix * 128 + gc);
          if (MODE == 2) {
            const uint4 r = *(const uint4*)(zr + pix * 256 + 128 + gc);
            v.x = mulbf2(v.x, r.x); v.y = mulbf2(v.y, r.y);
            v.z = mulbf2(v.z, r.z); v.w = mulbf2(v.w, r.w);
          }
        } else {
          v = *(const uint4*)(xb + pix * 256 + (gc - 128));
        }
      }
      *(uint4*)&als[(row * COLS + col) * CCP + cc8 * 8] = v;
    }
    __syncthreads();
    const int sbase = c64 * KHKW * 2;
#pragma unroll
    for (int kh = 0; kh < KH; ++kh) {
#pragma unroll
      for (int kw = 0; kw < KW; ++kw) {
#pragma unroll
        for (int half = 0; half < 2; ++half) {
          const int s = sbase + (kh * KW + kw) * 2 + half;
          const bfx8 a = *(const bfx8*)&als[kh * COLS * CCP + kw * CCP + half * 32 + aoff_lane];
          const bfx8 b0 = *(const bfx8*)(pb0 + (size_t)s * 512);
          const bfx8 b1 = *(const bfx8*)(pb1 + (size_t)s * 512);
          const bfx8 b2 = *(const bfx8*)(pb2 + (size_t)s * 512);
          const bfx8 b3 = *(const bfx8*)(pb3 + (size_t)s * 512);
          acc0 = __builtin_amdgcn_mfma_f32_16x16x32_bf16(a, b0, acc0, 0, 0, 0);
          acc1 = __builtin_amdgcn_mfma_f32_16x16x32_bf16(a, b1, acc1, 0, 0, 0);
          acc2 = __builtin_amdgcn_mfma_f32_16x16x32_bf16(a, b2, acc2, 0, 0, 0);
          acc3 = __builtin_amdgcn_mfma_f32_16x16x32_bf16(a, b3, acc3, 0, 0, 0);
        }
      }
    }
  }
  const f32x4 accs[4] = {acc0, acc1, acc2, acc3};
#pragma unroll
  for (int f = 0; f < 4; ++f) {
    const int co = (nbase + f) * 16 + m;
    const float b = bias[co];
#pragma unroll
    for (int reg = 0; reg < 4; ++reg) {
      const int row = q * 4 + reg;
      const int p = p0 + msub * 16 + row;
      float v = accs[f][reg] + b;
      if (ACT == 1) v = fmaxf(v, 0.f);
      if (ACT == 2) v = 1.f / (1.f + __expf(-v));
      if (ACT == 3) v = tanhf(v);
      v *= scale;
      const size_t pix = (size_t)nb * HW + p;
      if (UPD) {
        const float zv = bf2f(zr[pix * 256 + co]);
        const float old = bf2f(old_[pix * 128 + co]);
        v = (1.f - zv) * old + zv * v;
      }
      if (co_base + co < co_limit) {
        if (FOUT)
          ((float*)yv)[((size_t)nb * CO_TOT + co_base + co) * HW + p] = v;
        else
          ((ushort_t*)yv)[pix * CO_TOT + co_base + co] = f2bf(v);
      }
    }
  }
}

// ---------------------------------------------------------------------------
// mf1: 7x7 conv 2->128 + flow2x fused, branch-merged. grid (48, 4).
// ---------------------------------------------------------------------------
__global__ __launch_bounds__(256) void mf1_k(const float* __restrict__ fl0,
                                             const float* __restrict__ fl1,
                                             const float* __restrict__ w,
                                             const float* __restrict__ bias,
                                             ushort_t* __restrict__ flo0,
                                             ushort_t* __restrict__ flo1,
                                             ushort_t* __restrict__ X0,
                                             ushort_t* __restrict__ X1v) {
  __shared__ float wl[12544];
  const int tid = threadIdx.x;
  for (int e = tid; e < 12544; e += 256) {
    const int co = e & 127;
    const int rest = e >> 7;
    const int ci = rest / 49;
    const int t = rest - ci * 49;
    wl[e] = w[((size_t)co * 2 + ci) * 49 + t];
  }
  __syncthreads();
  const int zz = blockIdx.y;
  const int br = zz >> 1, nb = zz & 1;
  const float* flow = br ? fl1 : fl0;
  ushort_t* flo = br ? flo1 : flo0;
  ushort_t* X = br ? X1v : X0;
  const int p = blockIdx.x * 64 + (tid & 63);
  const int cg = (tid >> 6) * 32;
  const int y = p >> 6, x = p & 63;
  float acc[32];
#pragma unroll
  for (int c = 0; c < 32; ++c) acc[c] = bias[cg + c];
  for (int ci = 0; ci < 2; ++ci) {
    const float* fp = flow + (size_t)(nb * 2 + ci) * HW;
    for (int t = 0; t < 49; ++t) {
      const int gy = y + t / 7 - 3;
      const int gx = x + t % 7 - 3;
      float f = 0.f;
      if ((unsigned)gy < 48u && (unsigned)gx < 64u) f = fp[gy * 64 + gx];
      const float* wp = &wl[(ci * 49 + t) * 128 + cg];
#pragma unroll
      for (int c = 0; c < 32; ++c) acc[c] = fmaf(f, wp[c], acc[c]);
    }
  }
  ushort_t* op = flo + ((size_t)nb * HW + p) * 128 + cg;
#pragma unroll
  for (int c = 0; c < 32; ++c) op[c] = f2bf(fmaxf(acc[c], 0.f));
  if (tid < 64) {  // fused flow2x: X[254:256] = flow
    const float vx = flow[(size_t)(nb * 2 + 0) * HW + p];
    const float vy = flow[(size_t)(nb * 2 + 1) * HW + p];
    X[((size_t)nb * HW + p) * 256 + 254] = f2bf(vx);
    X[((size_t)nb * HW + p) * 256 + 255] = f2bf(vy);
  }
}

// ---------------------------------------------------------------------------
// small kernels
// ---------------------------------------------------------------------------
__global__ __launch_bounds__(256) void flow_update_k(float* __restrict__ flow,
                                                     float* __restrict__ eflow,
                                                     const float* __restrict__ df,
                                                     const float* __restrict__ edf) {
  int i = blockIdx.x * 256 + threadIdx.x;
  if (i < NB2 * 2 * HW) {
    float e = edf[i];
    flow[i] += df[i] + e;
    eflow[i] += e;
  }
}

__global__ __launch_bounds__(256) void upsample_k(const float* __restrict__ flow,
                                                  const ushort_t* __restrict__ mask,
                                                  float* __restrict__ out) {
  const int j = threadIdx.x & 7;
  const int xh = threadIdx.x >> 3;
  const int x = blockIdx.x * 32 + xh;
  const int i = blockIdx.y;
  const int nz = blockIdx.z;
  const int nb = nz / 48, yy = nz - nb * 48;
  const int rem = yy * 64 + x;
  const ushort_t* mp = mask + ((size_t)nb * HW + rem) * 576;
  float m[9];
  float mx = -1e30f;
#pragma unroll
  for (int k = 0; k < 9; ++k) {
    m[k] = bf2f(mp[k * 64 + i * 8 + j]);
    mx = fmaxf(mx, m[k]);
  }
  float sum = 0.f;
#pragma unroll
  for (int k = 0; k < 9; ++k) {
    m[k] = __expf(m[k] - mx);
    sum += m[k];
  }
  const float inv = 8.f / sum;
#pragma unroll
  for (int ch = 0; ch < 2; ++ch) {
    float acc = 0.f;
#pragma unroll
    for (int k = 0; k < 9; ++k) {
      const int gy = yy + k / 3 - 1;
      const int gx = x + (k - (k / 3) * 3) - 1;
      float f = 0.f;
      if ((unsigned)gy < 48u && (unsigned)gx < 64u)
        f = flow[((size_t)(nb * 2 + ch)) * HW + gy * 64 + gx];
      acc = fmaf(m[k], f, acc);
    }
    out[(((size_t)(nb * 2 + ch)) * 384 + (yy * 8 + i)) * 512 + x * 8 + j] = acc * inv;
  }
}

// ---------------------------------------------------------------------------
// host orchestration
// ---------------------------------------------------------------------------
extern "C" void kernel_launch(void* const* d_in, const int* in_sizes, int n_in,
                              void* d_out, int out_size, void* d_ws, size_t ws_size,
                              hipStream_t stream) {
  (void)in_sizes; (void)n_in; (void)out_size;

  size_t off = 0;
  char* base = (char*)d_ws;
  auto take = [&](size_t nbytes) -> void* {
    void* p = base + off;
    off += (nbytes + 255) & ~(size_t)255;
    return p;
  };
  ushort_t* pyrA[4];
  ushort_t* pyrB[4];
  const int lsz[4] = {3072, 768, 192, 48};
  for (int l = 0; l < 4; ++l) pyrA[l] = (ushort_t*)take((size_t)NP * lsz[l] * 2);
  for (int l = 0; l < 4; ++l) pyrB[l] = (ushort_t*)take((size_t)NP * lsz[l] * 2);
  ushort_t* FMT[4];
  for (int s = 0; s < 4; ++s) FMT[s] = (ushort_t*)take((size_t)NP * 256 * 2);
  ushort_t* CORRb[2];
  CORRb[0] = (ushort_t*)take((size_t)NP * 384 * 2);
  CORRb[1] = (ushort_t*)take((size_t)NP * 384 * 2);
  ushort_t* NETb[2];
  NETb[0] = (ushort_t*)take((size_t)NP * 128 * 2);
  NETb[1] = (ushort_t*)take((size_t)NP * 128 * 2);
  ushort_t* NETBb[2];
  NETBb[0] = (ushort_t*)take((size_t)NP * 128 * 2);
  NETBb[1] = (ushort_t*)take((size_t)NP * 128 * 2);
  ushort_t* Xb[2];
  Xb[0] = (ushort_t*)take((size_t)NP * 256 * 2);
  Xb[1] = (ushort_t*)take((size_t)NP * 256 * 2);
  ushort_t* ACT1b[2];
  ACT1b[0] = (ushort_t*)take((size_t)NP * 256 * 2);
  ACT1b[1] = (ushort_t*)take((size_t)NP * 256 * 2);
  ushort_t* CFBb[2];
  CFBb[0] = (ushort_t*)take((size_t)NP * 256 * 2);
  CFBb[1] = (ushort_t*)take((size_t)NP * 256 * 2);
  ushort_t* FLOb[2];
  FLOb[0] = (ushort_t*)take((size_t)NP * 128 * 2);
  FLOb[1] = (ushort_t*)take((size_t)NP * 128 * 2);
  ushort_t* ZRBb[2];
  ZRBb[0] = (ushort_t*)take((size_t)NP * 256 * 2);
  ZRBb[1] = (ushort_t*)take((size_t)NP * 256 * 2);
  ushort_t* A512b[2];
  A512b[0] = (ushort_t*)take((size_t)NP * 512 * 2);
  A512b[1] = (ushort_t*)take((size_t)NP * 512 * 2);
  ushort_t* MASKB = (ushort_t*)take((size_t)NP * 576 * 2);
  float* FLOW = (float*)take((size_t)NB2 * 2 * HW * 4);
  float* EFLOW = (float*)take((size_t)NB2 * 2 * HW * 4);
  float* DF = (float*)take((size_t)NB2 * 2 * HW * 4);
  float* EDF = (float*)take((size_t)NB2 * 2 * HW * 4);

  static const int WSZ[15] = {82944, 442368, 12544, 73728, 290304,
                              245760, 245760, 245760, 245760, 245760, 245760,
                              294912, 4608, 294912, 147456};
  static const int BSZ[15] = {256, 192, 128, 64, 126, 128, 128, 128,
                              128, 128, 128, 256, 2, 256, 576};
  float* Wf[15];
  float* Bf[15];
  for (int s = 0; s < 5; ++s) Wf[s] = (float*)take((size_t)WSZ[s] * 4);
  Wf[5] = (float*)take((size_t)2 * 245760 * 4); Wf[6] = Wf[5] + 245760;
  Wf[7] = (float*)take((size_t)245760 * 4);
  Wf[8] = (float*)take((size_t)2 * 245760 * 4); Wf[9] = Wf[8] + 245760;
  Wf[10] = (float*)take((size_t)245760 * 4);
  Wf[11] = (float*)take((size_t)2 * 294912 * 4); Wf[13] = Wf[11] + 294912;
  Wf[12] = (float*)take((size_t)4608 * 4);
  Wf[14] = (float*)take((size_t)147456 * 4);
  for (int s = 0; s < 5; ++s) Bf[s] = (float*)take((size_t)BSZ[s] * 4);
  Bf[5] = (float*)take((size_t)2 * 128 * 4); Bf[6] = Bf[5] + 128;
  Bf[7] = (float*)take((size_t)128 * 4);
  Bf[8] = (float*)take((size_t)2 * 128 * 4); Bf[9] = Bf[8] + 128;
  Bf[10] = (float*)take((size_t)128 * 4);
  Bf[11] = (float*)take((size_t)2 * 256 * 4); Bf[13] = Bf[11] + 256;
  Bf[12] = (float*)take((size_t)2 * 4);
  Bf[14] = (float*)take((size_t)576 * 4);
  ushort_t* PBmc1 = (ushort_t*)take((size_t)16 * 12 * 512 * 2);
  ushort_t* PBmc2 = (ushort_t*)take((size_t)16 * 72 * 512 * 2);
  ushort_t* PBmf2 = (ushort_t*)take((size_t)8 * 36 * 512 * 2);
  ushort_t* PBmo = (ushort_t*)take((size_t)8 * 72 * 512 * 2);
  ushort_t* PBgzr1 = (ushort_t*)take((size_t)16 * 60 * 512 * 2);
  ushort_t* PBgq1 = (ushort_t*)take((size_t)8 * 60 * 512 * 2);
  ushort_t* PBgzr2 = (ushort_t*)take((size_t)16 * 60 * 512 * 2);
  ushort_t* PBgq2 = (ushort_t*)take((size_t)8 * 60 * 512 * 2);
  ushort_t* PBfh = (ushort_t*)take((size_t)32 * 36 * 512 * 2);
  ushort_t* PBmk2 = (ushort_t*)take((size_t)40 * 8 * 512 * 2);
  ushort_t* PBfh2 = (ushort_t*)take((size_t)8 * 72 * 512 * 2);
  int* FLAG = (int*)take(256);

  if (off > ws_size) return;

  detect_k<<<1, 256, 0, stream>>>((const ushort_t*)d_in[0], FLAG);
  CvtArgs ca;
  for (int s = 0; s < 15; ++s) {
    ca.src[s] = d_in[6 + 2 * s];
    ca.dst[s] = Wf[s];
    ca.n[s] = WSZ[s];
    ca.src[15 + s] = d_in[7 + 2 * s];
    ca.dst[15 + s] = Bf[s];
    ca.n[15 + s] = BSZ[s];
  }
  cvt_all_k<<<512, 256, 0, stream>>>(ca, FLAG);

  trans_k<<<dim3((NP * 256 + 255) / 256, 4), 256, 0, stream>>>(
      d_in[0], d_in[1], d_in[2], d_in[3], FMT[0], FMT[1], FMT[2], FMT[3], FLAG);
  init2_k<<<dim3((NB2 * 128 * HW + 255) / 256, 2), 256, 0, stream>>>(
      d_in[4], d_in[5], NETb[0], NETb[1], Xb[0], Xb[1], FLAG);

  auto pack = [&](const float* src, ushort_t* dst, int CO, int NB16, int CI, int KHKW, int NCH) {
    int total = NB16 * NCH * KHKW * 2 * 512;
    pack_k<<<(total + 255) / 256, 256, 0, stream>>>(src, dst, CO, CI, KHKW, NCH, total);
  };
  pack(Wf[0], PBmc1, 256, 16, 324, 1, 6);
  pack(Wf[1], PBmc2, 192, 16, 256, 9, 4);
  pack(Wf[3], PBmf2, 64, 8, 128, 9, 2);
  pack(Wf[4], PBmo, 126, 8, 256, 9, 4);
  pack(Wf[5], PBgzr1, 256, 16, 384, 5, 6);
  pack(Wf[7], PBgq1, 128, 8, 384, 5, 6);
  pack(Wf[8], PBgzr2, 256, 16, 384, 5, 6);
  pack(Wf[10], PBgq2, 128, 8, 384, 5, 6);
  pack(Wf[11], PBfh, 512, 32, 128, 9, 2);
  pack(Wf[14], PBmk2, 576, 40, 256, 1, 4);
  pack(Wf[12], PBfh2, 2, 8, 256, 9, 4);

  {
    CorrPtrs cp;
    for (int s = 0; s < 4; ++s) cp.f[s] = FMT[s];
    cp.out[0] = pyrA[0];
    cp.out[1] = pyrB[0];
    corr_mfma_k<<<dim3(96, 24, 4), 256, 0, stream>>>(cp);
  }
  {
    const int wsv[4] = {64, 32, 16, 8};
    const int hsv[4] = {48, 24, 12, 6};
    for (int l = 0; l < 3; ++l) {
      int ho = hsv[l + 1], wo = wsv[l + 1];
      int total = NP * ho * wo;
      avgpool_k<<<dim3((total + 255) / 256, 2), 256, 0, stream>>>(
          pyrA[l], pyrB[l], pyrA[l + 1], pyrB[l + 1], wsv[l], ho, wo, total);
    }
  }
  (void)hipMemsetAsync(FLOW, 0, (size_t)NB2 * 2 * HW * 4, stream);
  (void)hipMemsetAsync(EFLOW, 0, (size_t)NB2 * 2 * HW * 4, stream);

  float* outp = (float*)d_out;

  LkPtrs lk;
  lk.a0 = pyrA[0]; lk.a1 = pyrA[1]; lk.a2 = pyrA[2]; lk.a3 = pyrA[3];
  lk.b0 = pyrB[0]; lk.b1 = pyrB[1]; lk.b2 = pyrB[2]; lk.b3 = pyrB[3];
  lk.flow[0] = FLOW; lk.flow[1] = EFLOW;
  lk.out[0] = CORRb[0]; lk.out[1] = CORRb[1];

  auto BP = [&](const ushort_t* a0, const ushort_t* a1, const ushort_t* b0,
                const ushort_t* b1, const ushort_t* z0, const ushort_t* z1,
                const ushort_t* o0, const ushort_t* o1, void* y0, void* y1) {
    BrPtrs p;
    p.xa[0] = a0; p.xa[1] = a1; p.xb[0] = b0; p.xb[1] = b1;
    p.zr[0] = z0; p.zr[1] = z1; p.old_[0] = o0; p.old_[1] = o1;
    p.y[0] = y0; p.y[1] = y1;
    return p;
  };
  const ushort_t* NU = nullptr;

  for (int it = 0; it < ITERS; ++it) {
    lookup_k<<<dim3(6144, 2), 384, 0, stream>>>(lk);
    // motion encoder
    conv_mfma_k<1, 1, 0, 0, 1, 0, false, false><<<dim3(96, 2, 4), 256, 0, stream>>>(
        BP(CORRb[0], CORRb[1], NU, NU, NU, NU, NU, NU, ACT1b[0], ACT1b[1]),
        PBmc1, Bf[0], 6, 384, 0, 0, 256, 256, 1.f, 2, 2);
    conv_mfma_k<3, 3, 1, 1, 1, 0, false, false><<<dim3(96, 2, 4), 256, 0, stream>>>(
        BP(ACT1b[0], ACT1b[1], NU, NU, NU, NU, NU, NU, CFBb[0], CFBb[1]),
        PBmc2, Bf[1], 4, 256, 0, 0, 256, 256, 1.f, 2, 2);
    mf1_k<<<dim3(48, 4), 256, 0, stream>>>(FLOW, EFLOW, Wf[2], Bf[2],
                                           FLOb[0], FLOb[1], Xb[0], Xb[1]);
    conv_mfma_k<3, 3, 1, 1, 1, 0, false, false><<<dim3(96, 1, 4), 256, 0, stream>>>(
        BP(FLOb[0], FLOb[1], NU, NU, NU, NU, NU, NU, CFBb[0], CFBb[1]),
        PBmf2, Bf[3], 2, 128, 0, 192, 256, 256, 1.f, 2, 1);
    conv_mfma_k<3, 3, 1, 1, 1, 0, false, false><<<dim3(96, 1, 4), 256, 0, stream>>>(
        BP(CFBb[0], CFBb[1], NU, NU, NU, NU, NU, NU, Xb[0], Xb[1]),
        PBmo, Bf[4], 4, 256, 0, 128, 256, 254, 1.f, 2, 1);
    // GRU horizontal (1x5)
    conv_mfma_k<1, 5, 0, 2, 2, 1, false, false><<<dim3(96, 2, 4), 256, 0, stream>>>(
        BP(NETb[0], NETb[1], Xb[0], Xb[1], NU, NU, NU, NU, ZRBb[0], ZRBb[1]),
        PBgzr1, Bf[5], 6, 0, 0, 0, 256, 256, 1.f, 2, 2);
    conv_mfma_k<1, 5, 0, 2, 3, 2, true, false><<<dim3(96, 1, 4), 256, 0, stream>>>(
        BP(NETb[0], NETb[1], Xb[0], Xb[1], ZRBb[0], ZRBb[1], NETb[0], NETb[1],
           NETBb[0], NETBb[1]),
        PBgq1, Bf[7], 6, 0, 0, 0, 128, 128, 1.f, 2, 1);
    // GRU vertical (5x1)
    conv_mfma_k<5, 1, 2, 0, 2, 1, false, false><<<dim3(96, 2, 4), 256, 0, stream>>>(
        BP(NETBb[0], NETBb[1], Xb[0], Xb[1], NU, NU, NU, NU, ZRBb[0], ZRBb[1]),
        PBgzr2, Bf[8], 6, 0, 0, 0, 256, 256, 1.f, 2, 2);
    conv_mfma_k<5, 1, 2, 0, 3, 2, true, false><<<dim3(96, 1, 4), 256, 0, stream>>>(
        BP(NETBb[0], NETBb[1], Xb[0], Xb[1], ZRBb[0], ZRBb[1], NETBb[0], NETBb[1],
           NETb[0], NETb[1]),
        PBgq2, Bf[10], 6, 0, 0, 0, 128, 128, 1.f, 2, 1);
    // heads
    conv_mfma_k<3, 3, 1, 1, 1, 0, false, false><<<dim3(96, 4, 4), 256, 0, stream>>>(
        BP(NETb[0], NETb[1], NU, NU, NU, NU, NU, NU, A512b[0], A512b[1]),
        PBfh, Bf[11], 2, 128, 0, 0, 512, 512, 1.f, 2, 2);
    conv_mfma_k<3, 3, 1, 1, 0, 0, false, true><<<dim3(96, 1, 4), 256, 0, stream>>>(
        BP(A512b[0], A512b[1], NU, NU, NU, NU, NU, NU, DF, EDF),
        PBfh2, Bf[12], 4, 512, 0, 0, 2, 2, 1.f, 2, 1);
    conv_mfma_k<1, 1, 0, 0, 0, 0, false, false><<<dim3(96, 5, 2), 256, 0, stream>>>(
        BP(A512b[0], NU, NU, NU, NU, NU, NU, NU, (void*)MASKB, nullptr),
        PBmk2, Bf[14], 4, 512, 256, 0, 576, 576, 0.25f, 1, 99);
    flow_update_k<<<48, 256, 0, stream>>>(FLOW, EFLOW, DF, EDF);
    upsample_k<<<dim3(2, 8, 96), 256, 0, stream>>>(FLOW, MASKB,
                                                   outp + (size_t)it * (NB2 * 2 * 384 * 512));
  }
}